// Round 3
// baseline (153.409 us; speedup 1.0000x reference)
//
#include <hip/hip_runtime.h>
#include <math.h>

#define N_    8
#define C_    512
#define HW_   1024
#define G_    32
#define CPG_  16
#define OC3_  1536
#define LOG2E 1.44269504f

typedef _Float16 f16;
typedef f16 f16x8 __attribute__((ext_vector_type(8)));
typedef f16 f16x4 __attribute__((ext_vector_type(4)));
typedef float f32x4 __attribute__((ext_vector_type(4)));

#define GLOAD_LDS16(g, l)                                                          \
    __builtin_amdgcn_global_load_lds(                                              \
        (const __attribute__((address_space(1))) unsigned int*)(const void*)(g),   \
        (__attribute__((address_space(3))) unsigned int*)(void*)(l), 16, 0, 0)

// s_waitcnt vmcnt(0) only (lgkmcnt=15, expcnt=7 -> no wait): simm16 = 0x0F70
#define WAIT_VM0() __builtin_amdgcn_s_waitcnt(0x0F70)

// ---------------- prep: GroupNorm+transpose (blocks 0..255) | weight pack (rest)
// XT is BLOCKED: [n][cb=c/16][l][16] so prep writes are fully coalesced
// (each thread writes 128 B contiguous).
__global__ __launch_bounds__(256) void prep(const float* __restrict__ x,
                                            const float* __restrict__ gw,
                                            const float* __restrict__ gb,
                                            f16* __restrict__ XT,
                                            const float* __restrict__ qkv_w,
                                            const float* __restrict__ out_w,
                                            const float* __restrict__ qkv_b,
                                            f16* __restrict__ Wq,
                                            f16* __restrict__ Wo,
                                            float* __restrict__ qkv_bs) {
    __shared__ float red1[4], red2[4];
    __shared__ float sm, srstd;
    if (blockIdx.x >= 256) {   // ---- weight pack path ----
        const float QS = 0.125f * LOG2E;
        int idx = (blockIdx.x - 256) * 256 + threadIdx.x;
        if (idx < 786432) {
            float v = qkv_w[idx];
            if (idx < 262144) v *= QS;              // q rows (o < 512)
            Wq[idx] = (f16)v;
        } else if (idx < 786432 + 262144) {
            Wo[idx - 786432] = (f16)out_w[idx - 786432];
        } else if (idx < 786432 + 262144 + 1536) {
            int i = idx - 786432 - 262144;
            float v = qkv_b[i];
            if (i < 512) v *= QS;
            qkv_bs[i] = v;
        }
        return;
    }
    // ---- GroupNorm path ----
    int blk = blockIdx.x;
    int n = blk >> 5, g = blk & 31;
    size_t base = ((size_t)n * C_ + (size_t)g * CPG_) * HW_;
    const float4* xp4 = (const float4*)(x + base);
    float4 vals[16];
    float s1 = 0.f, s2 = 0.f;
#pragma unroll
    for (int r = 0; r < 16; r++) {
        float4 v = xp4[r * 256 + threadIdx.x];   // c_local = r, l = 4*tid..4*tid+3
        vals[r] = v;
        s1 += v.x + v.y + v.z + v.w;
        s2 += v.x * v.x + v.y * v.y + v.z * v.z + v.w * v.w;
    }
#pragma unroll
    for (int off = 32; off > 0; off >>= 1) {
        s1 += __shfl_down(s1, off, 64);
        s2 += __shfl_down(s2, off, 64);
    }
    int wave = threadIdx.x >> 6, lane = threadIdx.x & 63;
    if (lane == 0) { red1[wave] = s1; red2[wave] = s2; }
    __syncthreads();
    if (threadIdx.x == 0) {
        float t1 = red1[0] + red1[1] + red1[2] + red1[3];
        float t2 = red2[0] + red2[1] + red2[2] + red2[3];
        float mean = t1 * (1.f / 16384.f);
        float var  = t2 * (1.f / 16384.f) - mean * mean;
        sm = mean;
        srstd = rsqrtf(var + 1e-5f);
    }
    __syncthreads();
    float mean = sm, rstd = srstd;
    float av[16], bbv[16];
#pragma unroll
    for (int r = 0; r < 16; r++) {
        int c = g * CPG_ + r;
        av[r] = gw[c] * rstd;
        bbv[r] = gb[c] - mean * av[r];
    }
    f16x8 lo[4], hi[4];
#pragma unroll
    for (int r = 0; r < 16; r++) {
        float4 v = vals[r];
        float a = av[r], bb = bbv[r];
        f16 e0 = (f16)(v.x * a + bb), e1 = (f16)(v.y * a + bb);
        f16 e2 = (f16)(v.z * a + bb), e3 = (f16)(v.w * a + bb);
        if (r < 8) { lo[0][r] = e0; lo[1][r] = e1; lo[2][r] = e2; lo[3][r] = e3; }
        else { hi[0][r - 8] = e0; hi[1][r - 8] = e1; hi[2][r - 8] = e2; hi[3][r - 8] = e3; }
    }
    // blocked store: [n][g][l][16], each thread 4 l's x 32 B contiguous = 128 B
    f16* xt = XT + (size_t)n * C_ * HW_ + ((size_t)g * HW_ + threadIdx.x * 4) * 16;
#pragma unroll
    for (int comp = 0; comp < 4; comp++) {
        *(f16x8*)&xt[comp * 16]     = lo[comp];
        *(f16x8*)&xt[comp * 16 + 8] = hi[comp];
    }
}

// ---------------- fp16 MFMA GEMM, DMA double-buffered prefetch pipeline -------
// Y[o][l] = sum_c A[o][c] * B[...] + bias. BK=32, 16 K-steps, one vmcnt(0)+
// one barrier per step; prefetch of step k+1 issued before computing step k
// (attn-style). Swizzle seg ^= (row>>1)&3 -> 2-way max bank aliasing (free).
// FINAL=false: BM=128, B is blocked XT [n][cb][l][16], grid 768 (3/CU).
// FINAL=true:  BM=64,  B is w2T [n][l][512],           grid 512 (2/CU).
template <bool FINAL>
__global__ __launch_bounds__(256, 4) void gemm_f16(const f16* __restrict__ A,
                                                   const f16* __restrict__ B,
                                                   const float* __restrict__ bias,
                                                   void* __restrict__ Yq,
                                                   f16* __restrict__ Yv) {
    constexpr int BM = FINAL ? 64 : 128;
    constexpr int MI = BM / 32;            // 16-row blocks per wave (wave owns BM/2)
    constexpr int AB = BM * 64;            // bytes per A buffer (BM x 32 f16)
    // layout: As0 @0, As1 @AB, Bs0 @2AB, Bs1 @2AB+8192 ; !FINAL T needs 34816
    __shared__ __align__(16) unsigned char smem[FINAL ? 24576 : 34816];
    int tid = threadIdx.x, lane = tid & 63, w = tid >> 6;
    int m = lane & 15, quad = lane >> 4;
    int ow0 = (w & 1) * (BM / 2), lw0 = (w >> 1) * 64;
    int flat = blockIdx.x;
    int n = flat & 7, rest = flat >> 3;
    int l0 = (rest & 7) * 128, o0 = (rest >> 3) * BM;
    const f16* Bn = B + (size_t)n * C_ * HW_;   // 512*1024 elements either layout

    f32x4 acc[MI][4];
#pragma unroll
    for (int i = 0; i < MI; i++)
#pragma unroll
        for (int j = 0; j < 4; j++)
#pragma unroll
            for (int r = 0; r < 4; r++) acc[i][j][r] = 0.f;

    // ---- staging helper (inlined twice): DMA one BK=32 slab into buffer pb
#define STAGE_STEP(c0_, pb_)                                                       \
    do {                                                                           \
        _Pragma("unroll")                                                          \
        for (int it = 0; it < BM / 64; it++) {                                     \
            int q = it * 256 + tid;                                                \
            int row = q >> 2, sg = (q & 3) ^ ((row >> 1) & 3);                     \
            GLOAD_LDS16(A + (size_t)(o0 + row) * 512 + (c0_) + sg * 8,             \
                        (f16*)(smem + (pb_) * AB) + (size_t)(it * 256 + w * 64) * 8); \
        }                                                                          \
        _Pragma("unroll")                                                          \
        for (int it = 0; it < 2; it++) {                                           \
            int q = it * 256 + tid;                                                \
            int row = q >> 2, sg = (q & 3) ^ ((row >> 1) & 3);                     \
            size_t baddr;                                                          \
            if (FINAL) {                                                           \
                baddr = (size_t)(l0 + row) * 512 + (c0_) + sg * 8;                 \
            } else {                                                               \
                int c = (c0_) + sg * 8;                                            \
                baddr = ((size_t)(c >> 4) * HW_ + (l0 + row)) * 16 + (c & 15);     \
            }                                                                      \
            GLOAD_LDS16(Bn + baddr,                                                \
                        (f16*)(smem + 2 * AB + (pb_) * 8192) +                     \
                            (size_t)(it * 256 + w * 64) * 8);                      \
        }                                                                          \
    } while (0)

    STAGE_STEP(0, 0);                       // prologue: stage step 0 -> buffer 0

    for (int cs = 0; cs < 16; cs++) {
        int p = cs & 1;
        WAIT_VM0();                         // own DMA for buffer p landed
        __syncthreads();                    // everyone's landed; prev reads done
        if (cs < 15) STAGE_STEP((cs + 1) * 32, 1 - p);   // prefetch next slab
        const f16* Asp = (const f16*)(smem + p * AB);
        const f16* Bsp = (const f16*)(smem + 2 * AB + p * 8192);
        f16x8 af[MI], bf[4];
#pragma unroll
        for (int ib = 0; ib < MI; ib++) {
            int row = ow0 + ib * 16 + m;
            int sg = quad ^ ((row >> 1) & 3);
            af[ib] = *(const f16x8*)&Asp[row * 32 + sg * 8];
        }
#pragma unroll
        for (int jb = 0; jb < 4; jb++) {
            int row = lw0 + jb * 16 + m;
            int sg = quad ^ ((row >> 1) & 3);
            bf[jb] = *(const f16x8*)&Bsp[row * 32 + sg * 8];
        }
#pragma unroll
        for (int ib = 0; ib < MI; ib++)
#pragma unroll
            for (int jb = 0; jb < 4; jb++)
                acc[ib][jb] = __builtin_amdgcn_mfma_f32_16x16x32_f16(
                    af[ib], bf[jb], acc[ib][jb], 0, 0, 0);
    }
#undef STAGE_STEP

    float bv[MI][4];
#pragma unroll
    for (int ib = 0; ib < MI; ib++)
#pragma unroll
        for (int r = 0; r < 4; r++)
            bv[ib][r] = bias[o0 + ow0 + ib * 16 + quad * 4 + r];

    if (FINAL) {
        float* on = (float*)Yq + (size_t)n * C_ * HW_;
#pragma unroll
        for (int ib = 0; ib < MI; ib++)
#pragma unroll
            for (int jb = 0; jb < 4; jb++)
#pragma unroll
                for (int r = 0; r < 4; r++)
                    on[(size_t)(o0 + ow0 + ib * 16 + quad * 4 + r) * HW_ +
                       l0 + lw0 + jb * 16 + m] = acc[ib][jb][r] + bv[ib][r];
    } else if (o0 >= 1024) {
        f16* vn = Yv + (size_t)n * C_ * HW_;
#pragma unroll
        for (int ib = 0; ib < MI; ib++)
#pragma unroll
            for (int jb = 0; jb < 4; jb++)
#pragma unroll
                for (int r = 0; r < 4; r++)
                    vn[(size_t)(o0 - 1024 + ow0 + ib * 16 + quad * 4 + r) * HW_ +
                       l0 + lw0 + jb * 16 + m] = (f16)(acc[ib][jb][r] + bv[ib][r]);
    } else {
        __syncthreads();                 // staging reads done; reuse smem
        f16* T = (f16*)smem;             // [128][136]
#pragma unroll
        for (int ib = 0; ib < MI; ib++)
#pragma unroll
            for (int jb = 0; jb < 4; jb++) {
                f16x4 h;
#pragma unroll
                for (int r = 0; r < 4; r++) h[r] = (f16)(acc[ib][jb][r] + bv[ib][r]);
                int l = lw0 + jb * 16 + m;
                int oo = ow0 + ib * 16 + quad * 4;
                *(f16x4*)&T[l * 136 + oo] = h;
            }
        __syncthreads();
        f16* qn = (f16*)Yq + (size_t)n * HW_ * 1024;
#pragma unroll
        for (int rep = 0; rep < 8; rep++) {
            int idx = rep * 256 + tid;
            int l = idx >> 4, seg = idx & 15;
            f16x8 v = *(const f16x8*)&T[l * 136 + seg * 8];
            *(f16x8*)&qn[(size_t)(l0 + l) * 1024 + o0 + seg * 8] = v;
        }
    }
}

// ---------------- Flash attention fp16 MFMA, 64-row i-tiles ----------------
// S^T form (mfma(K,Q)); DMA-dbuf K/V; ONE 16-row strip per wave. P is consumed
// IN-REGISTER by 16x16x16 PV MFMAs (S^T output layout == x16 A-frag layout),
// so the P LDS round-trip is gone entirely. LDS 32 KB -> 4 blocks/CU.
// grid 1024 flat, XCD-swizzled.
__global__ __launch_bounds__(256, 4) void attn_f16(const f16* __restrict__ qkvT,
                                                   const f16* __restrict__ vbuf,
                                                   f16* __restrict__ w2T) {
    __shared__ __align__(16) unsigned char smem[32768];
    f16* Kb0  = (f16*)smem;                 // two 8 KB K buffers at 0, 8192
    f16* Vb0  = (f16*)(smem + 16384);       // two 8 KB V buffers at 16384, 24576
    f16* LDSo = (f16*)smem;                 // epilogue alias of K area (8 KB)

    int tid = threadIdx.x;
    int lane = tid & 63, wave = tid >> 6;
    int m = lane & 15, quad = lane >> 4;
    // XCD swizzle: flat = ((itile*8 + bh_hi)*8) + xcd ; bh = bh_hi*8 + xcd
    int flat = blockIdx.x;                  // 1024 blocks
    int xcd = flat & 7, slot = flat >> 3;
    int itile = slot >> 3, bh = (slot & 7) * 8 + xcd;
    int n = bh >> 3, head = bh & 7;
    int i0 = itile * 64;
    const f16* qb = qkvT + (size_t)n * HW_ * 1024 + head * 64;
    const f16* kb = qb + 512;
    const f16* vb = vbuf + (size_t)n * C_ * HW_ + (size_t)head * 64 * HW_;

    // Q fragments for this wave's strip (rows i0 + wave*16 + m)
    const f16* qr = qb + (size_t)(i0 + wave * 16 + m) * 1024;
    f16x8 aq0 = *(const f16x8*)&qr[quad * 8];
    f16x8 aq1 = *(const f16x8*)&qr[32 + quad * 8];

    // stage tile 0 -> buffer 0 (async)
#pragma unroll
    for (int it = 0; it < 2; it++) {
        int chunk = it * 256 + tid;
        int row = chunk >> 3, seg = chunk & 7;
        int segg = seg ^ (row & 7);
        GLOAD_LDS16(kb + (size_t)row * 1024 + segg * 8,
                    Kb0 + ((size_t)it * 256 + wave * 64) * 8);
        GLOAD_LDS16(vb + (size_t)row * HW_ + segg * 8,
                    Vb0 + ((size_t)it * 256 + wave * 64) * 8);
    }

    f32x4 oacc[4];
#pragma unroll
    for (int cb = 0; cb < 4; cb++)
#pragma unroll
        for (int r = 0; r < 4; r++) oacc[cb][r] = 0.f;
    float lsum = 0.f;
    int m7 = m & 7;

    for (int jt = 0; jt < 16; jt++) {
        int p = jt & 1;
        const f16* Kp = Kb0 + p * 4096;
        const f16* Vp = Vb0 + p * 4096;
        WAIT_VM0();        // drain own LDS-DMA before the barrier
        __syncthreads();   // all waves aligned => buffer p fully written
        if (jt < 15) {     // prefetch tile jt+1 into the other buffer
            int j0n = (jt + 1) * 64;
            f16* Kn = Kb0 + (1 - p) * 4096;
            f16* Vn = Vb0 + (1 - p) * 4096;
#pragma unroll
            for (int it = 0; it < 2; it++) {
                int chunk = it * 256 + tid;
                int row = chunk >> 3, seg = chunk & 7;
                int segg = seg ^ (row & 7);
                GLOAD_LDS16(kb + (size_t)(j0n + row) * 1024 + segg * 8,
                            Kn + ((size_t)it * 256 + wave * 64) * 8);
                GLOAD_LDS16(vb + (size_t)row * HW_ + j0n + segg * 8,
                            Vn + ((size_t)it * 256 + wave * 64) * 8);
            }
        }

        // K fragments (A-operand of S^T MFMA): rows j = jb*16 + m
        f16x8 kf[8];
#pragma unroll
        for (int jb = 0; jb < 4; jb++) {
            int row = jb * 16 + m;
            kf[jb]     = *(const f16x8*)&Kp[row * 64 + ((quad ^ (row & 7)) * 8)];
            kf[4 + jb] = *(const f16x8*)&Kp[row * 64 + (((4 + quad) ^ (row & 7)) * 8)];
        }

        // S^T = K Q^T : lane holds S[i=m][j = jb*16 + quad*4 + r]
        f32x4 sacc[4];
#pragma unroll
        for (int jb = 0; jb < 4; jb++)
#pragma unroll
            for (int r = 0; r < 4; r++) sacc[jb][r] = 0.f;
#pragma unroll
        for (int jb = 0; jb < 4; jb++)
            sacc[jb] = __builtin_amdgcn_mfma_f32_16x16x32_f16(kf[jb], aq0,
                                                              sacc[jb], 0, 0, 0);
#pragma unroll
        for (int jb = 0; jb < 4; jb++)
            sacc[jb] = __builtin_amdgcn_mfma_f32_16x16x32_f16(kf[4 + jb], aq1,
                                                              sacc[jb], 0, 0, 0);

        // max-free softmax: p = 2^s (log2 scale folded into Wq); pack P as
        // the x16 A-fragment DIRECTLY (lane layout matches, no cross-lane move)
        f16x4 pf[4];
#pragma unroll
        for (int jb = 0; jb < 4; jb++) {
            float p0 = exp2f(sacc[jb][0]), p1 = exp2f(sacc[jb][1]);
            float p2 = exp2f(sacc[jb][2]), p3 = exp2f(sacc[jb][3]);
            lsum += (p0 + p1) + (p2 + p3);
            pf[jb][0] = (f16)p0; pf[jb][1] = (f16)p1;
            pf[jb][2] = (f16)p2; pf[jb][3] = (f16)p3;
        }

        // O += P V via 16x16x16: B-frag lane (m,q) needs V[jb*16+q*4+r][cb*16+m],
        // contiguous f16x4 in the Vb[c][j] row (seg-swizzle on c&7 == m&7).
#pragma unroll
        for (int jb = 0; jb < 4; jb++) {
            int segb = jb * 2 + (quad >> 1);
#pragma unroll
            for (int cb = 0; cb < 4; cb++) {
                f16x4 vf4 = *(const f16x4*)&Vp[(cb * 16 + m) * 64 +
                                               ((segb ^ m7) * 8) + (quad & 1) * 4];
                oacc[cb] = __builtin_amdgcn_mfma_f32_16x16x16f16(pf[jb], vf4,
                                                                 oacc[cb], 0, 0, 0);
            }
        }
    }

    // row sums; lane's partial is for strip row m
    float ls = lsum;
    ls += __shfl_xor(ls, 16, 64);
    ls += __shfl_xor(ls, 32, 64);
    float linv[4];
#pragma unroll
    for (int r = 0; r < 4; r++) linv[r] = 1.f / __shfl(ls, quad * 4 + r, 64);

    WAIT_VM0();
    __syncthreads();   // everyone done with K/V buffers before aliasing
    // torch-reshape epilogue: local row li = wave*16+quad*4+r ->
    // ch-slot = li>>4 = wave ; s-coord = (li&15)*64 + cb*16 + m
#pragma unroll
    for (int cb = 0; cb < 4; cb++)
#pragma unroll
        for (int r = 0; r < 4; r++) {
            int sc = (quad * 4 + r) * 64 + cb * 16 + m;
            LDSo[sc * 4 + wave] = (f16)(oacc[cb][r] * linv[r]);
        }
    __syncthreads();
    f16* w2n = w2T + (size_t)n * HW_ * 512;
    int chbase = head * 64 + (i0 >> 4);     // itile*4 -> 8B aligned
#pragma unroll
    for (int it = 0; it < 4; it++) {
        int sc = it * 256 + tid;
        *(f16x4*)&w2n[(size_t)sc * 512 + chbase] = *(const f16x4*)&LDSo[sc * 4];
    }
}

extern "C" void kernel_launch(void* const* d_in, const int* in_sizes, int n_in,
                              void* d_out, int out_size, void* d_ws, size_t ws_size,
                              hipStream_t stream) {
    (void)in_sizes; (void)n_in; (void)out_size; (void)ws_size;
    const float* x     = (const float*)d_in[0];
    const float* gw    = (const float*)d_in[1];
    const float* gb    = (const float*)d_in[2];
    const float* qkv_w = (const float*)d_in[3];
    const float* qkv_b = (const float*)d_in[4];
    const float* out_w = (const float*)d_in[5];
    const float* out_b = (const float*)d_in[6];
    float* out = (float*)d_out;
    char* ws = (char*)d_ws;

    const size_t MB = 1024 * 1024;
    f16*   qkvT   = (f16*)ws;                       // [8][1024][1024] q|k  (16 MB)
    f16*   XT     = (f16*)(ws + 16 * MB);           // blocked [8][32][1024][16] (8 MB)
    f16*   vbuf   = (f16*)(ws + 24 * MB);           // [8][512][1024]       (8 MB)
    f16*   w2T    = (f16*)(ws + 32 * MB);           // [8][1024][512]       (8 MB)
    f16*   Wq     = (f16*)(ws + 40 * MB);           // [1536][512]          (1.5 MB)
    f16*   Wo     = (f16*)(ws + 42 * MB);           // [512][512]           (0.5 MB)
    float* qkv_bs = (float*)(ws + 43 * MB);         // [1536]

    prep<<<dim3(256 + 4103), 256, 0, stream>>>(x, gw, gb, XT,
                                               qkv_w, out_w, qkv_b, Wq, Wo, qkv_bs);
    gemm_f16<false><<<dim3(768), 256, 0, stream>>>(Wq, XT, qkv_bs, (void*)qkvT, vbuf);
    attn_f16<<<dim3(1024), 256, 0, stream>>>(qkvT, vbuf, w2T);
    gemm_f16<true><<<dim3(512), 256, 0, stream>>>(Wo, w2T, out_b, (void*)out, nullptr);
}

// Round 4
// 149.050 us; speedup vs baseline: 1.0292x; 1.0292x over previous
//
#include <hip/hip_runtime.h>
#include <math.h>

#define N_    8
#define C_    512
#define HW_   1024
#define G_    32
#define CPG_  16
#define OC3_  1536
#define LOG2E 1.44269504f

typedef _Float16 f16;
typedef f16 f16x8 __attribute__((ext_vector_type(8)));
typedef f16 f16x4 __attribute__((ext_vector_type(4)));
typedef float f32x4 __attribute__((ext_vector_type(4)));

#define GLOAD_LDS16(g, l)                                                          \
    __builtin_amdgcn_global_load_lds(                                              \
        (const __attribute__((address_space(1))) unsigned int*)(const void*)(g),   \
        (__attribute__((address_space(3))) unsigned int*)(void*)(l), 16, 0, 0)

// s_waitcnt encodings: vmcnt in [3:0], expcnt=7 (no wait) in [6:4],
// lgkmcnt=15 (no wait) in [11:8]  ->  0x0F70 | vmcnt
#define WAIT_VM0() __builtin_amdgcn_s_waitcnt(0x0F70)

// ---------------- prep: GroupNorm+transpose (blocks 0..255) | weight pack (rest)
__global__ __launch_bounds__(256) void prep(const float* __restrict__ x,
                                            const float* __restrict__ gw,
                                            const float* __restrict__ gb,
                                            f16* __restrict__ XT,
                                            const float* __restrict__ qkv_w,
                                            const float* __restrict__ out_w,
                                            const float* __restrict__ qkv_b,
                                            f16* __restrict__ Wq,
                                            f16* __restrict__ Wo,
                                            float* __restrict__ qkv_bs) {
    __shared__ float red1[4], red2[4];
    __shared__ float sm, srstd;
    if (blockIdx.x >= 256) {   // ---- weight pack path ----
        const float QS = 0.125f * LOG2E;
        int idx = (blockIdx.x - 256) * 256 + threadIdx.x;
        if (idx < 786432) {
            float v = qkv_w[idx];
            if (idx < 262144) v *= QS;              // q rows (o < 512)
            Wq[idx] = (f16)v;
        } else if (idx < 786432 + 262144) {
            Wo[idx - 786432] = (f16)out_w[idx - 786432];
        } else if (idx < 786432 + 262144 + 1536) {
            int i = idx - 786432 - 262144;
            float v = qkv_b[i];
            if (i < 512) v *= QS;
            qkv_bs[i] = v;
        }
        return;
    }
    // ---- GroupNorm path ----
    int blk = blockIdx.x;
    int n = blk >> 5, g = blk & 31;
    size_t base = ((size_t)n * C_ + (size_t)g * CPG_) * HW_;
    const float4* xp4 = (const float4*)(x + base);
    float4 vals[16];
    float s1 = 0.f, s2 = 0.f;
#pragma unroll
    for (int r = 0; r < 16; r++) {
        float4 v = xp4[r * 256 + threadIdx.x];   // c_local = r, l = 4*tid..4*tid+3
        vals[r] = v;
        s1 += v.x + v.y + v.z + v.w;
        s2 += v.x * v.x + v.y * v.y + v.z * v.z + v.w * v.w;
    }
#pragma unroll
    for (int off = 32; off > 0; off >>= 1) {
        s1 += __shfl_down(s1, off, 64);
        s2 += __shfl_down(s2, off, 64);
    }
    int wave = threadIdx.x >> 6, lane = threadIdx.x & 63;
    if (lane == 0) { red1[wave] = s1; red2[wave] = s2; }
    __syncthreads();
    if (threadIdx.x == 0) {
        float t1 = red1[0] + red1[1] + red1[2] + red1[3];
        float t2 = red2[0] + red2[1] + red2[2] + red2[3];
        float mean = t1 * (1.f / 16384.f);
        float var  = t2 * (1.f / 16384.f) - mean * mean;
        sm = mean;
        srstd = rsqrtf(var + 1e-5f);
    }
    __syncthreads();
    float mean = sm, rstd = srstd;
    float av[16], bbv[16];
#pragma unroll
    for (int r = 0; r < 16; r++) {
        int c = g * CPG_ + r;
        av[r] = gw[c] * rstd;
        bbv[r] = gb[c] - mean * av[r];
    }
    f16x8 lo[4], hi[4];
#pragma unroll
    for (int r = 0; r < 16; r++) {
        float4 v = vals[r];
        float a = av[r], bb = bbv[r];
        f16 e0 = (f16)(v.x * a + bb), e1 = (f16)(v.y * a + bb);
        f16 e2 = (f16)(v.z * a + bb), e3 = (f16)(v.w * a + bb);
        if (r < 8) { lo[0][r] = e0; lo[1][r] = e1; lo[2][r] = e2; lo[3][r] = e3; }
        else { hi[0][r - 8] = e0; hi[1][r - 8] = e1; hi[2][r - 8] = e2; hi[3][r - 8] = e3; }
    }
    // blocked store: [n][g][l][16], each thread 4 l's x 32 B contiguous = 128 B
    f16* xt = XT + (size_t)n * C_ * HW_ + ((size_t)g * HW_ + threadIdx.x * 4) * 16;
#pragma unroll
    for (int comp = 0; comp < 4; comp++) {
        *(f16x8*)&xt[comp * 16]     = lo[comp];
        *(f16x8*)&xt[comp * 16 + 8] = hi[comp];
    }
}

// ---------------- fp16 MFMA GEMM, depth-2 DMA pipeline, counted vmcnt ---------
// Y[o][l] = sum_c A[o][c] * B[...] + bias. BK=32, 16 K-steps, 3 LDS buffers.
// Step k: waitcnt vmcnt(G) certifies tile k landed (k+1 in flight); raw
// s_barrier collectivizes; stage tile k+2; compute tile k. Loads get 2 full
// compute phases to land (T4). Swizzle seg^=(row>>1)&3 (2-way max, free).
// FINAL=false: BM=128, B blocked XT [n][cb][l][16], grid 768 (3/CU, 48KB).
// FINAL=true:  BM=64,  B w2T [n][l][512],           grid 512 (2/CU, 36KB).
template <bool FINAL>
__global__ __launch_bounds__(256, 4) void gemm_f16(const f16* __restrict__ A,
                                                   const f16* __restrict__ B,
                                                   const float* __restrict__ bias,
                                                   void* __restrict__ Yq,
                                                   f16* __restrict__ Yv) {
    constexpr int BM = FINAL ? 64 : 128;
    constexpr int MI = BM / 32;            // 16-row blocks per wave (wave owns BM/2)
    constexpr int ABUF = BM * 32 * 2;      // bytes per A buffer
    constexpr int BBUF = 128 * 32 * 2;     // 8192 bytes per B buffer
    constexpr int G = (BM / 64) + 2;       // per-thread GLOADs per stage
    // A bufs at 0,ABUF,2ABUF ; B bufs at 3ABUF + p*BBUF. !FINAL: 49152 (>=34816 T)
    __shared__ __align__(16) unsigned char smem[3 * ABUF + 3 * BBUF];
    int tid = threadIdx.x, lane = tid & 63, w = tid >> 6;
    int m = lane & 15, quad = lane >> 4;
    int ow0 = (w & 1) * (BM / 2), lw0 = (w >> 1) * 64;
    int flat = blockIdx.x;
    int n = flat & 7, rest = flat >> 3;
    int l0 = (rest & 7) * 128, o0 = (rest >> 3) * BM;
    const f16* Bn = B + (size_t)n * C_ * HW_;   // 512*1024 elements either layout

    f32x4 acc[MI][4];
#pragma unroll
    for (int i = 0; i < MI; i++)
#pragma unroll
        for (int j = 0; j < 4; j++)
#pragma unroll
            for (int r = 0; r < 4; r++) acc[i][j][r] = 0.f;

#define STAGE_STEP(c0_, pb_)                                                       \
    do {                                                                           \
        _Pragma("unroll")                                                          \
        for (int it = 0; it < BM / 64; it++) {                                     \
            int q = it * 256 + tid;                                                \
            int row = q >> 2, sg = (q & 3) ^ ((row >> 1) & 3);                     \
            GLOAD_LDS16(A + (size_t)(o0 + row) * 512 + (c0_) + sg * 8,             \
                        (f16*)(smem + (pb_) * ABUF) + (size_t)(it * 256 + w * 64) * 8); \
        }                                                                          \
        _Pragma("unroll")                                                          \
        for (int it = 0; it < 2; it++) {                                           \
            int q = it * 256 + tid;                                                \
            int row = q >> 2, sg = (q & 3) ^ ((row >> 1) & 3);                     \
            size_t baddr;                                                          \
            if (FINAL) {                                                           \
                baddr = (size_t)(l0 + row) * 512 + (c0_) + sg * 8;                 \
            } else {                                                               \
                int c = (c0_) + sg * 8;                                            \
                baddr = ((size_t)(c >> 4) * HW_ + (l0 + row)) * 16 + (c & 15);     \
            }                                                                      \
            GLOAD_LDS16(Bn + baddr,                                                \
                        (f16*)(smem + 3 * ABUF + (pb_) * BBUF) +                   \
                            (size_t)(it * 256 + w * 64) * 8);                      \
        }                                                                          \
    } while (0)

    STAGE_STEP(0, 0);                       // prologue: tiles 0 and 1 in flight
    STAGE_STEP(32, 1);

    for (int cs = 0; cs < 16; cs++) {
        int p = cs % 3;
        if (cs < 15) __builtin_amdgcn_s_waitcnt(0x0F70 | G);  // tile cs landed
        else         WAIT_VM0();                              // tail: only G left
        __builtin_amdgcn_s_barrier();       // all waves certified + done reading
        if (cs + 2 < 16) STAGE_STEP((cs + 2) * 32, (cs + 2) % 3);
        const f16* Asp = (const f16*)(smem + p * ABUF);
        const f16* Bsp = (const f16*)(smem + 3 * ABUF + p * BBUF);
        f16x8 af[MI], bf[4];
#pragma unroll
        for (int ib = 0; ib < MI; ib++) {
            int row = ow0 + ib * 16 + m;
            int sg = quad ^ ((row >> 1) & 3);
            af[ib] = *(const f16x8*)&Asp[row * 32 + sg * 8];
        }
#pragma unroll
        for (int jb = 0; jb < 4; jb++) {
            int row = lw0 + jb * 16 + m;
            int sg = quad ^ ((row >> 1) & 3);
            bf[jb] = *(const f16x8*)&Bsp[row * 32 + sg * 8];
        }
#pragma unroll
        for (int ib = 0; ib < MI; ib++)
#pragma unroll
            for (int jb = 0; jb < 4; jb++)
                acc[ib][jb] = __builtin_amdgcn_mfma_f32_16x16x32_f16(
                    af[ib], bf[jb], acc[ib][jb], 0, 0, 0);
    }
#undef STAGE_STEP

    float bv[MI][4];
#pragma unroll
    for (int ib = 0; ib < MI; ib++)
#pragma unroll
        for (int r = 0; r < 4; r++)
            bv[ib][r] = bias[o0 + ow0 + ib * 16 + quad * 4 + r];

    if (FINAL) {
        float* on = (float*)Yq + (size_t)n * C_ * HW_;
#pragma unroll
        for (int ib = 0; ib < MI; ib++)
#pragma unroll
            for (int jb = 0; jb < 4; jb++)
#pragma unroll
                for (int r = 0; r < 4; r++)
                    on[(size_t)(o0 + ow0 + ib * 16 + quad * 4 + r) * HW_ +
                       l0 + lw0 + jb * 16 + m] = acc[ib][jb][r] + bv[ib][r];
    } else if (o0 >= 1024) {
        f16* vn = Yv + (size_t)n * C_ * HW_;
#pragma unroll
        for (int ib = 0; ib < MI; ib++)
#pragma unroll
            for (int jb = 0; jb < 4; jb++)
#pragma unroll
                for (int r = 0; r < 4; r++)
                    vn[(size_t)(o0 - 1024 + ow0 + ib * 16 + quad * 4 + r) * HW_ +
                       l0 + lw0 + jb * 16 + m] = (f16)(acc[ib][jb][r] + bv[ib][r]);
    } else {
        __syncthreads();                 // staging reads done; reuse smem
        f16* T = (f16*)smem;             // [128][136]
#pragma unroll
        for (int ib = 0; ib < MI; ib++)
#pragma unroll
            for (int jb = 0; jb < 4; jb++) {
                f16x4 h;
#pragma unroll
                for (int r = 0; r < 4; r++) h[r] = (f16)(acc[ib][jb][r] + bv[ib][r]);
                int l = lw0 + jb * 16 + m;
                int oo = ow0 + ib * 16 + quad * 4;
                *(f16x4*)&T[l * 136 + oo] = h;
            }
        __syncthreads();
        f16* qn = (f16*)Yq + (size_t)n * HW_ * 1024;
#pragma unroll
        for (int rep = 0; rep < 8; rep++) {
            int idx = rep * 256 + tid;
            int l = idx >> 4, seg = idx & 15;
            f16x8 v = *(const f16x8*)&T[l * 136 + seg * 8];
            *(f16x8*)&qn[(size_t)(l0 + l) * 1024 + o0 + seg * 8] = v;
        }
    }
}

// ---------------- Flash attention fp16 MFMA, 64-row i-tiles, depth-2 pipeline --
// S^T form (mfma(K,Q)); 3-buffer K/V DMA pipeline with counted vmcnt (same
// scheme as gemm). P consumed IN-REGISTER by 16x16x16 PV MFMAs. LDS 48 KB ->
// 3 blocks/CU. grid 1024 flat, XCD-swizzled.
__global__ __launch_bounds__(256, 4) void attn_f16(const f16* __restrict__ qkvT,
                                                   const f16* __restrict__ vbuf,
                                                   f16* __restrict__ w2T) {
    __shared__ __align__(16) unsigned char smem[49152];
    // K bufs at 0,8192,16384 ; V bufs at 24576,32768,40960
    f16* LDSo = (f16*)smem;                 // epilogue alias (8 KB)

    int tid = threadIdx.x;
    int lane = tid & 63, wave = tid >> 6;
    int m = lane & 15, quad = lane >> 4;
    // XCD swizzle: flat = ((itile*8 + bh_hi)*8) + xcd ; bh = bh_hi*8 + xcd
    int flat = blockIdx.x;                  // 1024 blocks
    int xcd = flat & 7, slot = flat >> 3;
    int itile = slot >> 3, bh = (slot & 7) * 8 + xcd;
    int n = bh >> 3, head = bh & 7;
    int i0 = itile * 64;
    const f16* qb = qkvT + (size_t)n * HW_ * 1024 + head * 64;
    const f16* kb = qb + 512;
    const f16* vb = vbuf + (size_t)n * C_ * HW_ + (size_t)head * 64 * HW_;

    // Q fragments for this wave's strip (rows i0 + wave*16 + m)
    const f16* qr = qb + (size_t)(i0 + wave * 16 + m) * 1024;
    f16x8 aq0 = *(const f16x8*)&qr[quad * 8];
    f16x8 aq1 = *(const f16x8*)&qr[32 + quad * 8];

#define STAGE_KV(j0_, pb_)                                                         \
    do {                                                                           \
        _Pragma("unroll")                                                          \
        for (int it = 0; it < 2; it++) {                                           \
            int chunk = it * 256 + tid;                                            \
            int row = chunk >> 3, seg = chunk & 7;                                 \
            int segg = seg ^ (row & 7);                                            \
            GLOAD_LDS16(kb + (size_t)((j0_) + row) * 1024 + segg * 8,              \
                        (f16*)(smem + (pb_) * 8192) +                              \
                            ((size_t)it * 256 + wave * 64) * 8);                   \
            GLOAD_LDS16(vb + (size_t)row * HW_ + (j0_) + segg * 8,                 \
                        (f16*)(smem + 24576 + (pb_) * 8192) +                      \
                            ((size_t)it * 256 + wave * 64) * 8);                   \
        }                                                                          \
    } while (0)

    STAGE_KV(0, 0);                         // tiles 0 and 1 in flight
    STAGE_KV(64, 1);

    f32x4 oacc[4];
#pragma unroll
    for (int cb = 0; cb < 4; cb++)
#pragma unroll
        for (int r = 0; r < 4; r++) oacc[cb][r] = 0.f;
    float lsum = 0.f;
    int m7 = m & 7;

    for (int jt = 0; jt < 16; jt++) {
        int p = jt % 3;
        if (jt < 15) __builtin_amdgcn_s_waitcnt(0x0F74);  // tile jt landed (G=4)
        else         WAIT_VM0();
        __builtin_amdgcn_s_barrier();
        if (jt + 2 < 16) STAGE_KV((jt + 2) * 64, (jt + 2) % 3);
        const f16* Kp = (const f16*)(smem + p * 8192);
        const f16* Vp = (const f16*)(smem + 24576 + p * 8192);

        // K fragments (A-operand of S^T MFMA): rows j = jb*16 + m
        f16x8 kf[8];
#pragma unroll
        for (int jb = 0; jb < 4; jb++) {
            int row = jb * 16 + m;
            kf[jb]     = *(const f16x8*)&Kp[row * 64 + ((quad ^ (row & 7)) * 8)];
            kf[4 + jb] = *(const f16x8*)&Kp[row * 64 + (((4 + quad) ^ (row & 7)) * 8)];
        }

        // S^T = K Q^T : lane holds S[i=m][j = jb*16 + quad*4 + r]
        f32x4 sacc[4];
#pragma unroll
        for (int jb = 0; jb < 4; jb++)
#pragma unroll
            for (int r = 0; r < 4; r++) sacc[jb][r] = 0.f;
#pragma unroll
        for (int jb = 0; jb < 4; jb++)
            sacc[jb] = __builtin_amdgcn_mfma_f32_16x16x32_f16(kf[jb], aq0,
                                                              sacc[jb], 0, 0, 0);
#pragma unroll
        for (int jb = 0; jb < 4; jb++)
            sacc[jb] = __builtin_amdgcn_mfma_f32_16x16x32_f16(kf[4 + jb], aq1,
                                                              sacc[jb], 0, 0, 0);

        // max-free softmax: p = 2^s (log2 scale folded into Wq); pack P as
        // the x16 A-fragment DIRECTLY (lane layout matches, no cross-lane move)
        f16x4 pf[4];
#pragma unroll
        for (int jb = 0; jb < 4; jb++) {
            float p0 = exp2f(sacc[jb][0]), p1 = exp2f(sacc[jb][1]);
            float p2 = exp2f(sacc[jb][2]), p3 = exp2f(sacc[jb][3]);
            lsum += (p0 + p1) + (p2 + p3);
            pf[jb][0] = (f16)p0; pf[jb][1] = (f16)p1;
            pf[jb][2] = (f16)p2; pf[jb][3] = (f16)p3;
        }

        // O += P V via 16x16x16: B-frag lane (m,q) needs V[jb*16+q*4+r][cb*16+m],
        // contiguous f16x4 in the Vb[c][j] row (seg-swizzle on c&7 == m&7).
#pragma unroll
        for (int jb = 0; jb < 4; jb++) {
            int segb = jb * 2 + (quad >> 1);
#pragma unroll
            for (int cb = 0; cb < 4; cb++) {
                f16x4 vf4 = *(const f16x4*)&Vp[(cb * 16 + m) * 64 +
                                               ((segb ^ m7) * 8) + (quad & 1) * 4];
                oacc[cb] = __builtin_amdgcn_mfma_f32_16x16x16f16(pf[jb], vf4,
                                                                 oacc[cb], 0, 0, 0);
            }
        }
    }
#undef STAGE_KV

    // row sums; lane's partial is for strip row m
    float ls = lsum;
    ls += __shfl_xor(ls, 16, 64);
    ls += __shfl_xor(ls, 32, 64);
    float linv[4];
#pragma unroll
    for (int r = 0; r < 4; r++) linv[r] = 1.f / __shfl(ls, quad * 4 + r, 64);

    WAIT_VM0();
    __syncthreads();   // everyone done with K/V buffers before aliasing
    // torch-reshape epilogue: local row li = wave*16+quad*4+r ->
    // ch-slot = li>>4 = wave ; s-coord = (li&15)*64 + cb*16 + m
#pragma unroll
    for (int cb = 0; cb < 4; cb++)
#pragma unroll
        for (int r = 0; r < 4; r++) {
            int sc = (quad * 4 + r) * 64 + cb * 16 + m;
            LDSo[sc * 4 + wave] = (f16)(oacc[cb][r] * linv[r]);
        }
    __syncthreads();
    f16* w2n = w2T + (size_t)n * HW_ * 512;
    int chbase = head * 64 + (i0 >> 4);     // itile*4 -> 8B aligned
#pragma unroll
    for (int it = 0; it < 4; it++) {
        int sc = it * 256 + tid;
        *(f16x4*)&w2n[(size_t)sc * 512 + chbase] = *(const f16x4*)&LDSo[sc * 4];
    }
}

extern "C" void kernel_launch(void* const* d_in, const int* in_sizes, int n_in,
                              void* d_out, int out_size, void* d_ws, size_t ws_size,
                              hipStream_t stream) {
    (void)in_sizes; (void)n_in; (void)out_size; (void)ws_size;
    const float* x     = (const float*)d_in[0];
    const float* gw    = (const float*)d_in[1];
    const float* gb    = (const float*)d_in[2];
    const float* qkv_w = (const float*)d_in[3];
    const float* qkv_b = (const float*)d_in[4];
    const float* out_w = (const float*)d_in[5];
    const float* out_b = (const float*)d_in[6];
    float* out = (float*)d_out;
    char* ws = (char*)d_ws;

    const size_t MB = 1024 * 1024;
    f16*   qkvT   = (f16*)ws;                       // [8][1024][1024] q|k  (16 MB)
    f16*   XT     = (f16*)(ws + 16 * MB);           // blocked [8][32][1024][16] (8 MB)
    f16*   vbuf   = (f16*)(ws + 24 * MB);           // [8][512][1024]       (8 MB)
    f16*   w2T    = (f16*)(ws + 32 * MB);           // [8][1024][512]       (8 MB)
    f16*   Wq     = (f16*)(ws + 40 * MB);           // [1536][512]          (1.5 MB)
    f16*   Wo     = (f16*)(ws + 42 * MB);           // [512][512]           (0.5 MB)
    float* qkv_bs = (float*)(ws + 43 * MB);         // [1536]

    prep<<<dim3(256 + 4103), 256, 0, stream>>>(x, gw, gb, XT,
                                               qkv_w, out_w, qkv_b, Wq, Wo, qkv_bs);
    gemm_f16<false><<<dim3(768), 256, 0, stream>>>(Wq, XT, qkv_bs, (void*)qkvT, vbuf);
    attn_f16<<<dim3(1024), 256, 0, stream>>>(qkvT, vbuf, w2T);
    gemm_f16<true><<<dim3(512), 256, 0, stream>>>(Wo, w2T, out_b, (void*)out, nullptr);
}

// Round 5
// 145.896 us; speedup vs baseline: 1.0515x; 1.0216x over previous
//
#include <hip/hip_runtime.h>
#include <math.h>

#define N_    8
#define C_    512
#define HW_   1024
#define G_    32
#define CPG_  16
#define OC3_  1536
#define LOG2E 1.44269504f

typedef _Float16 f16;
typedef f16 f16x8 __attribute__((ext_vector_type(8)));
typedef f16 f16x4 __attribute__((ext_vector_type(4)));
typedef float f32x4 __attribute__((ext_vector_type(4)));

#define GLOAD_LDS16(g, l)                                                          \
    __builtin_amdgcn_global_load_lds(                                              \
        (const __attribute__((address_space(1))) unsigned int*)(const void*)(g),   \
        (__attribute__((address_space(3))) unsigned int*)(void*)(l), 16, 0, 0)

// s_waitcnt encodings: vmcnt in [3:0], expcnt=7 (no wait) in [6:4],
// lgkmcnt=15 (no wait) in [11:8]  ->  0x0F70 | vmcnt
#define WAIT_VM0() __builtin_amdgcn_s_waitcnt(0x0F70)

// ---------------- prep: GroupNorm+transpose (blocks 0..255) | weight pack (rest)
__global__ __launch_bounds__(256) void prep(const float* __restrict__ x,
                                            const float* __restrict__ gw,
                                            const float* __restrict__ gb,
                                            f16* __restrict__ XT,
                                            const float* __restrict__ qkv_w,
                                            const float* __restrict__ out_w,
                                            const float* __restrict__ qkv_b,
                                            f16* __restrict__ Wq,
                                            f16* __restrict__ Wo,
                                            float* __restrict__ qkv_bs) {
    __shared__ float red1[4], red2[4];
    __shared__ float sm, srstd;
    if (blockIdx.x >= 256) {   // ---- weight pack path ----
        const float QS = 0.125f * LOG2E;
        int idx = (blockIdx.x - 256) * 256 + threadIdx.x;
        if (idx < 786432) {
            float v = qkv_w[idx];
            if (idx < 262144) v *= QS;              // q rows (o < 512)
            Wq[idx] = (f16)v;
        } else if (idx < 786432 + 262144) {
            Wo[idx - 786432] = (f16)out_w[idx - 786432];
        } else if (idx < 786432 + 262144 + 1536) {
            int i = idx - 786432 - 262144;
            float v = qkv_b[i];
            if (i < 512) v *= QS;
            qkv_bs[i] = v;
        }
        return;
    }
    // ---- GroupNorm path ----
    int blk = blockIdx.x;
    int n = blk >> 5, g = blk & 31;
    size_t base = ((size_t)n * C_ + (size_t)g * CPG_) * HW_;
    const float4* xp4 = (const float4*)(x + base);
    float4 vals[16];
    float s1 = 0.f, s2 = 0.f;
#pragma unroll
    for (int r = 0; r < 16; r++) {
        float4 v = xp4[r * 256 + threadIdx.x];   // c_local = r, l = 4*tid..4*tid+3
        vals[r] = v;
        s1 += v.x + v.y + v.z + v.w;
        s2 += v.x * v.x + v.y * v.y + v.z * v.z + v.w * v.w;
    }
#pragma unroll
    for (int off = 32; off > 0; off >>= 1) {
        s1 += __shfl_down(s1, off, 64);
        s2 += __shfl_down(s2, off, 64);
    }
    int wave = threadIdx.x >> 6, lane = threadIdx.x & 63;
    if (lane == 0) { red1[wave] = s1; red2[wave] = s2; }
    __syncthreads();
    if (threadIdx.x == 0) {
        float t1 = red1[0] + red1[1] + red1[2] + red1[3];
        float t2 = red2[0] + red2[1] + red2[2] + red2[3];
        float mean = t1 * (1.f / 16384.f);
        float var  = t2 * (1.f / 16384.f) - mean * mean;
        sm = mean;
        srstd = rsqrtf(var + 1e-5f);
    }
    __syncthreads();
    float mean = sm, rstd = srstd;
    float av[16], bbv[16];
#pragma unroll
    for (int r = 0; r < 16; r++) {
        int c = g * CPG_ + r;
        av[r] = gw[c] * rstd;
        bbv[r] = gb[c] - mean * av[r];
    }
    f16x8 lo[4], hi[4];
#pragma unroll
    for (int r = 0; r < 16; r++) {
        float4 v = vals[r];
        float a = av[r], bb = bbv[r];
        f16 e0 = (f16)(v.x * a + bb), e1 = (f16)(v.y * a + bb);
        f16 e2 = (f16)(v.z * a + bb), e3 = (f16)(v.w * a + bb);
        if (r < 8) { lo[0][r] = e0; lo[1][r] = e1; lo[2][r] = e2; lo[3][r] = e3; }
        else { hi[0][r - 8] = e0; hi[1][r - 8] = e1; hi[2][r - 8] = e2; hi[3][r - 8] = e3; }
    }
    // blocked store: [n][g][l][16], each thread 4 l's x 32 B contiguous = 128 B
    f16* xt = XT + (size_t)n * C_ * HW_ + ((size_t)g * HW_ + threadIdx.x * 4) * 16;
#pragma unroll
    for (int comp = 0; comp < 4; comp++) {
        *(f16x8*)&xt[comp * 16]     = lo[comp];
        *(f16x8*)&xt[comp * 16 + 8] = hi[comp];
    }
}

// ---------------- fp16 MFMA GEMM, depth-2 DMA pipeline, counted vmcnt ---------
// Y[o][l] = sum_c A[o][c] * B[...] + bias. BK=32, 16 K-steps, 3 LDS buffers.
// Step k: waitcnt vmcnt(G) certifies tile k landed (k+1 in flight); raw
// s_barrier collectivizes; stage tile k+2; compute tile k. Loads get 2 full
// compute phases to land (T4). Swizzle seg^=(row>>1)&3 (2-way max, free).
// FINAL=false: BM=128, B blocked XT [n][cb][l][16], grid 768 (3/CU, 48KB).
// FINAL=true:  BM=64,  B w2T [n][l][512],           grid 512 (2/CU, 36KB).
template <bool FINAL>
__global__ __launch_bounds__(256, 4) void gemm_f16(const f16* __restrict__ A,
                                                   const f16* __restrict__ B,
                                                   const float* __restrict__ bias,
                                                   void* __restrict__ Yq,
                                                   f16* __restrict__ Yv) {
    constexpr int BM = FINAL ? 64 : 128;
    constexpr int MI = BM / 32;            // 16-row blocks per wave (wave owns BM/2)
    constexpr int ABUF = BM * 32 * 2;      // bytes per A buffer
    constexpr int BBUF = 128 * 32 * 2;     // 8192 bytes per B buffer
    constexpr int G = (BM / 64) + 2;       // per-thread GLOADs per stage
    // A bufs at 0,ABUF,2ABUF ; B bufs at 3ABUF + p*BBUF. !FINAL: 49152 (>=34816 T)
    __shared__ __align__(16) unsigned char smem[3 * ABUF + 3 * BBUF];
    int tid = threadIdx.x, lane = tid & 63, w = tid >> 6;
    int m = lane & 15, quad = lane >> 4;
    int ow0 = (w & 1) * (BM / 2), lw0 = (w >> 1) * 64;
    int flat = blockIdx.x;
    int n = flat & 7, rest = flat >> 3;
    int l0 = (rest & 7) * 128, o0 = (rest >> 3) * BM;
    const f16* Bn = B + (size_t)n * C_ * HW_;   // 512*1024 elements either layout

    f32x4 acc[MI][4];
#pragma unroll
    for (int i = 0; i < MI; i++)
#pragma unroll
        for (int j = 0; j < 4; j++)
#pragma unroll
            for (int r = 0; r < 4; r++) acc[i][j][r] = 0.f;

#define STAGE_STEP(c0_, pb_)                                                       \
    do {                                                                           \
        _Pragma("unroll")                                                          \
        for (int it = 0; it < BM / 64; it++) {                                     \
            int q = it * 256 + tid;                                                \
            int row = q >> 2, sg = (q & 3) ^ ((row >> 1) & 3);                     \
            GLOAD_LDS16(A + (size_t)(o0 + row) * 512 + (c0_) + sg * 8,             \
                        (f16*)(smem + (pb_) * ABUF) + (size_t)(it * 256 + w * 64) * 8); \
        }                                                                          \
        _Pragma("unroll")                                                          \
        for (int it = 0; it < 2; it++) {                                           \
            int q = it * 256 + tid;                                                \
            int row = q >> 2, sg = (q & 3) ^ ((row >> 1) & 3);                     \
            size_t baddr;                                                          \
            if (FINAL) {                                                           \
                baddr = (size_t)(l0 + row) * 512 + (c0_) + sg * 8;                 \
            } else {                                                               \
                int c = (c0_) + sg * 8;                                            \
                baddr = ((size_t)(c >> 4) * HW_ + (l0 + row)) * 16 + (c & 15);     \
            }                                                                      \
            GLOAD_LDS16(Bn + baddr,                                                \
                        (f16*)(smem + 3 * ABUF + (pb_) * BBUF) +                   \
                            (size_t)(it * 256 + w * 64) * 8);                      \
        }                                                                          \
    } while (0)

    STAGE_STEP(0, 0);                       // prologue: tiles 0 and 1 in flight
    STAGE_STEP(32, 1);

    for (int cs = 0; cs < 16; cs++) {
        int p = cs % 3;
        if (cs < 15) __builtin_amdgcn_s_waitcnt(0x0F70 | G);  // tile cs landed
        else         WAIT_VM0();                              // tail: only G left
        __builtin_amdgcn_s_barrier();       // all waves certified + done reading
        if (cs + 2 < 16) STAGE_STEP((cs + 2) * 32, (cs + 2) % 3);
        const f16* Asp = (const f16*)(smem + p * ABUF);
        const f16* Bsp = (const f16*)(smem + 3 * ABUF + p * BBUF);
        f16x8 af[MI], bf[4];
#pragma unroll
        for (int ib = 0; ib < MI; ib++) {
            int row = ow0 + ib * 16 + m;
            int sg = quad ^ ((row >> 1) & 3);
            af[ib] = *(const f16x8*)&Asp[row * 32 + sg * 8];
        }
#pragma unroll
        for (int jb = 0; jb < 4; jb++) {
            int row = lw0 + jb * 16 + m;
            int sg = quad ^ ((row >> 1) & 3);
            bf[jb] = *(const f16x8*)&Bsp[row * 32 + sg * 8];
        }
#pragma unroll
        for (int ib = 0; ib < MI; ib++)
#pragma unroll
            for (int jb = 0; jb < 4; jb++)
                acc[ib][jb] = __builtin_amdgcn_mfma_f32_16x16x32_f16(
                    af[ib], bf[jb], acc[ib][jb], 0, 0, 0);
    }
#undef STAGE_STEP

    float bv[MI][4];
#pragma unroll
    for (int ib = 0; ib < MI; ib++)
#pragma unroll
        for (int r = 0; r < 4; r++)
            bv[ib][r] = bias[o0 + ow0 + ib * 16 + quad * 4 + r];

    if (FINAL) {
        float* on = (float*)Yq + (size_t)n * C_ * HW_;
#pragma unroll
        for (int ib = 0; ib < MI; ib++)
#pragma unroll
            for (int jb = 0; jb < 4; jb++)
#pragma unroll
                for (int r = 0; r < 4; r++)
                    on[(size_t)(o0 + ow0 + ib * 16 + quad * 4 + r) * HW_ +
                       l0 + lw0 + jb * 16 + m] = acc[ib][jb][r] + bv[ib][r];
    } else if (o0 >= 1024) {
        f16* vn = Yv + (size_t)n * C_ * HW_;
#pragma unroll
        for (int ib = 0; ib < MI; ib++)
#pragma unroll
            for (int jb = 0; jb < 4; jb++)
#pragma unroll
                for (int r = 0; r < 4; r++)
                    vn[(size_t)(o0 - 1024 + ow0 + ib * 16 + quad * 4 + r) * HW_ +
                       l0 + lw0 + jb * 16 + m] = (f16)(acc[ib][jb][r] + bv[ib][r]);
    } else {
        __syncthreads();                 // staging reads done; reuse smem
        f16* T = (f16*)smem;             // [128][136]
#pragma unroll
        for (int ib = 0; ib < MI; ib++)
#pragma unroll
            for (int jb = 0; jb < 4; jb++) {
                f16x4 h;
#pragma unroll
                for (int r = 0; r < 4; r++) h[r] = (f16)(acc[ib][jb][r] + bv[ib][r]);
                int l = lw0 + jb * 16 + m;
                int oo = ow0 + ib * 16 + quad * 4;
                *(f16x4*)&T[l * 136 + oo] = h;
            }
        __syncthreads();
        f16* qn = (f16*)Yq + (size_t)n * HW_ * 1024;
#pragma unroll
        for (int rep = 0; rep < 8; rep++) {
            int idx = rep * 256 + tid;
            int l = idx >> 4, seg = idx & 15;
            f16x8 v = *(const f16x8*)&T[l * 136 + seg * 8];
            *(f16x8*)&qn[(size_t)(l0 + l) * 1024 + o0 + seg * 8] = v;
        }
    }
}

// ---------------- Flash attention fp16 MFMA, 64-row i-tiles ----------------
// S^T form (mfma(K,Q)); 2-buffer K/V DMA prefetch (1 phase deep — enough to
// cover L2 latency; 3-buffer depth-2 measured SLOWER: 4->3 blocks/CU).
// P consumed IN-REGISTER by 16x16x16 PV MFMAs. LDS 32 KB -> 4 blocks/CU.
// s_setprio(1) around MFMA clusters (T5). grid 1024 flat, XCD-swizzled.
__global__ __launch_bounds__(256, 4) void attn_f16(const f16* __restrict__ qkvT,
                                                   const f16* __restrict__ vbuf,
                                                   f16* __restrict__ w2T) {
    __shared__ __align__(16) unsigned char smem[32768];
    f16* Kb0  = (f16*)smem;                 // two 8 KB K buffers at 0, 8192
    f16* Vb0  = (f16*)(smem + 16384);       // two 8 KB V buffers at 16384, 24576
    f16* LDSo = (f16*)smem;                 // epilogue alias of K area (8 KB)

    int tid = threadIdx.x;
    int lane = tid & 63, wave = tid >> 6;
    int m = lane & 15, quad = lane >> 4;
    // XCD swizzle: flat = ((itile*8 + bh_hi)*8) + xcd ; bh = bh_hi*8 + xcd
    int flat = blockIdx.x;                  // 1024 blocks
    int xcd = flat & 7, slot = flat >> 3;
    int itile = slot >> 3, bh = (slot & 7) * 8 + xcd;
    int n = bh >> 3, head = bh & 7;
    int i0 = itile * 64;
    const f16* qb = qkvT + (size_t)n * HW_ * 1024 + head * 64;
    const f16* kb = qb + 512;
    const f16* vb = vbuf + (size_t)n * C_ * HW_ + (size_t)head * 64 * HW_;

    // Q fragments for this wave's strip (rows i0 + wave*16 + m)
    const f16* qr = qb + (size_t)(i0 + wave * 16 + m) * 1024;
    f16x8 aq0 = *(const f16x8*)&qr[quad * 8];
    f16x8 aq1 = *(const f16x8*)&qr[32 + quad * 8];

    // stage tile 0 -> buffer 0 (async)
#pragma unroll
    for (int it = 0; it < 2; it++) {
        int chunk = it * 256 + tid;
        int row = chunk >> 3, seg = chunk & 7;
        int segg = seg ^ (row & 7);
        GLOAD_LDS16(kb + (size_t)row * 1024 + segg * 8,
                    Kb0 + ((size_t)it * 256 + wave * 64) * 8);
        GLOAD_LDS16(vb + (size_t)row * HW_ + segg * 8,
                    Vb0 + ((size_t)it * 256 + wave * 64) * 8);
    }

    f32x4 oacc[4];
#pragma unroll
    for (int cb = 0; cb < 4; cb++)
#pragma unroll
        for (int r = 0; r < 4; r++) oacc[cb][r] = 0.f;
    float lsum = 0.f;
    int m7 = m & 7;

    for (int jt = 0; jt < 16; jt++) {
        int p = jt & 1;
        const f16* Kp = Kb0 + p * 4096;
        const f16* Vp = Vb0 + p * 4096;
        WAIT_VM0();        // drain own LDS-DMA before the barrier
        __syncthreads();   // all waves aligned => buffer p fully written
        if (jt < 15) {     // prefetch tile jt+1 into the other buffer
            int j0n = (jt + 1) * 64;
            f16* Kn = Kb0 + (1 - p) * 4096;
            f16* Vn = Vb0 + (1 - p) * 4096;
#pragma unroll
            for (int it = 0; it < 2; it++) {
                int chunk = it * 256 + tid;
                int row = chunk >> 3, seg = chunk & 7;
                int segg = seg ^ (row & 7);
                GLOAD_LDS16(kb + (size_t)(j0n + row) * 1024 + segg * 8,
                            Kn + ((size_t)it * 256 + wave * 64) * 8);
                GLOAD_LDS16(vb + (size_t)row * HW_ + j0n + segg * 8,
                            Vn + ((size_t)it * 256 + wave * 64) * 8);
            }
        }

        // K fragments (A-operand of S^T MFMA): rows j = jb*16 + m
        f16x8 kf[8];
#pragma unroll
        for (int jb = 0; jb < 4; jb++) {
            int row = jb * 16 + m;
            kf[jb]     = *(const f16x8*)&Kp[row * 64 + ((quad ^ (row & 7)) * 8)];
            kf[4 + jb] = *(const f16x8*)&Kp[row * 64 + (((4 + quad) ^ (row & 7)) * 8)];
        }

        // S^T = K Q^T : lane holds S[i=m][j = jb*16 + quad*4 + r]
        f32x4 sacc[4];
#pragma unroll
        for (int jb = 0; jb < 4; jb++)
#pragma unroll
            for (int r = 0; r < 4; r++) sacc[jb][r] = 0.f;
        __builtin_amdgcn_s_setprio(1);
#pragma unroll
        for (int jb = 0; jb < 4; jb++)
            sacc[jb] = __builtin_amdgcn_mfma_f32_16x16x32_f16(kf[jb], aq0,
                                                              sacc[jb], 0, 0, 0);
#pragma unroll
        for (int jb = 0; jb < 4; jb++)
            sacc[jb] = __builtin_amdgcn_mfma_f32_16x16x32_f16(kf[4 + jb], aq1,
                                                              sacc[jb], 0, 0, 0);
        __builtin_amdgcn_s_setprio(0);

        // max-free softmax: p = 2^s (log2 scale folded into Wq); pack P as
        // the x16 A-fragment DIRECTLY (lane layout matches, no cross-lane move)
        f16x4 pf[4];
#pragma unroll
        for (int jb = 0; jb < 4; jb++) {
            float p0 = exp2f(sacc[jb][0]), p1 = exp2f(sacc[jb][1]);
            float p2 = exp2f(sacc[jb][2]), p3 = exp2f(sacc[jb][3]);
            lsum += (p0 + p1) + (p2 + p3);
            pf[jb][0] = (f16)p0; pf[jb][1] = (f16)p1;
            pf[jb][2] = (f16)p2; pf[jb][3] = (f16)p3;
        }

        // O += P V via 16x16x16: B-frag lane (m,q) needs V[jb*16+q*4+r][cb*16+m],
        // contiguous f16x4 in the Vb[c][j] row (seg-swizzle on c&7 == m&7).
        __builtin_amdgcn_s_setprio(1);
#pragma unroll
        for (int jb = 0; jb < 4; jb++) {
            int segb = jb * 2 + (quad >> 1);
#pragma unroll
            for (int cb = 0; cb < 4; cb++) {
                f16x4 vf4 = *(const f16x4*)&Vp[(cb * 16 + m) * 64 +
                                               ((segb ^ m7) * 8) + (quad & 1) * 4];
                oacc[cb] = __builtin_amdgcn_mfma_f32_16x16x16f16(pf[jb], vf4,
                                                                 oacc[cb], 0, 0, 0);
            }
        }
        __builtin_amdgcn_s_setprio(0);
    }

    // row sums; lane's partial is for strip row m
    float ls = lsum;
    ls += __shfl_xor(ls, 16, 64);
    ls += __shfl_xor(ls, 32, 64);
    float linv[4];
#pragma unroll
    for (int r = 0; r < 4; r++) linv[r] = 1.f / __shfl(ls, quad * 4 + r, 64);

    WAIT_VM0();
    __syncthreads();   // everyone done with K/V buffers before aliasing
    // torch-reshape epilogue: local row li = wave*16+quad*4+r ->
    // ch-slot = li>>4 = wave ; s-coord = (li&15)*64 + cb*16 + m
#pragma unroll
    for (int cb = 0; cb < 4; cb++)
#pragma unroll
        for (int r = 0; r < 4; r++) {
            int sc = (quad * 4 + r) * 64 + cb * 16 + m;
            LDSo[sc * 4 + wave] = (f16)(oacc[cb][r] * linv[r]);
        }
    __syncthreads();
    f16* w2n = w2T + (size_t)n * HW_ * 512;
    int chbase = head * 64 + (i0 >> 4);     // itile*4 -> 8B aligned
#pragma unroll
    for (int it = 0; it < 4; it++) {
        int sc = it * 256 + tid;
        *(f16x4*)&w2n[(size_t)sc * 512 + chbase] = *(const f16x4*)&LDSo[sc * 4];
    }
}

extern "C" void kernel_launch(void* const* d_in, const int* in_sizes, int n_in,
                              void* d_out, int out_size, void* d_ws, size_t ws_size,
                              hipStream_t stream) {
    (void)in_sizes; (void)n_in; (void)out_size; (void)ws_size;
    const float* x     = (const float*)d_in[0];
    const float* gw    = (const float*)d_in[1];
    const float* gb    = (const float*)d_in[2];
    const float* qkv_w = (const float*)d_in[3];
    const float* qkv_b = (const float*)d_in[4];
    const float* out_w = (const float*)d_in[5];
    const float* out_b = (const float*)d_in[6];
    float* out = (float*)d_out;
    char* ws = (char*)d_ws;

    const size_t MB = 1024 * 1024;
    f16*   qkvT   = (f16*)ws;                       // [8][1024][1024] q|k  (16 MB)
    f16*   XT     = (f16*)(ws + 16 * MB);           // blocked [8][32][1024][16] (8 MB)
    f16*   vbuf   = (f16*)(ws + 24 * MB);           // [8][512][1024]       (8 MB)
    f16*   w2T    = (f16*)(ws + 32 * MB);           // [8][1024][512]       (8 MB)
    f16*   Wq     = (f16*)(ws + 40 * MB);           // [1536][512]          (1.5 MB)
    f16*   Wo     = (f16*)(ws + 42 * MB);           // [512][512]           (0.5 MB)
    float* qkv_bs = (float*)(ws + 43 * MB);         // [1536]

    prep<<<dim3(256 + 4103), 256, 0, stream>>>(x, gw, gb, XT,
                                               qkv_w, out_w, qkv_b, Wq, Wo, qkv_bs);
    gemm_f16<false><<<dim3(768), 256, 0, stream>>>(Wq, XT, qkv_bs, (void*)qkvT, vbuf);
    attn_f16<<<dim3(1024), 256, 0, stream>>>(qkvT, vbuf, w2T);
    gemm_f16<true><<<dim3(512), 256, 0, stream>>>(Wo, w2T, out_b, (void*)out, nullptr);
}

// Round 6
// 140.744 us; speedup vs baseline: 1.0900x; 1.0366x over previous
//
#include <hip/hip_runtime.h>
#include <math.h>

#define N_    8
#define C_    512
#define HW_   1024
#define G_    32
#define CPG_  16
#define OC3_  1536
#define LOG2E 1.44269504f

typedef _Float16 f16;
typedef f16 f16x8 __attribute__((ext_vector_type(8)));
typedef f16 f16x4 __attribute__((ext_vector_type(4)));
typedef f16 f16x2 __attribute__((ext_vector_type(2)));
typedef float f32x4 __attribute__((ext_vector_type(4)));

#if __has_builtin(__builtin_amdgcn_exp2f)
#define EXP2F(x) __builtin_amdgcn_exp2f(x)
#else
#define EXP2F(x) exp2f(x)
#endif

#define GLOAD_LDS16(g, l)                                                          \
    __builtin_amdgcn_global_load_lds(                                              \
        (const __attribute__((address_space(1))) unsigned int*)(const void*)(g),   \
        (__attribute__((address_space(3))) unsigned int*)(void*)(l), 16, 0, 0)

// s_waitcnt encodings: vmcnt in [3:0], expcnt=7 (no wait) in [6:4],
// lgkmcnt=15 (no wait) in [11:8]  ->  0x0F70 | vmcnt
#define WAIT_VM0() __builtin_amdgcn_s_waitcnt(0x0F70)

// ---------------- prep: GroupNorm+transpose (blocks 0..255) | weight pack (rest)
__global__ __launch_bounds__(256) void prep(const float* __restrict__ x,
                                            const float* __restrict__ gw,
                                            const float* __restrict__ gb,
                                            f16* __restrict__ XT,
                                            const float* __restrict__ qkv_w,
                                            const float* __restrict__ out_w,
                                            const float* __restrict__ qkv_b,
                                            f16* __restrict__ Wq,
                                            f16* __restrict__ Wo,
                                            float* __restrict__ qkv_bs) {
    __shared__ float red1[4], red2[4];
    __shared__ float sm, srstd;
    if (blockIdx.x >= 256) {   // ---- weight pack path ----
        const float QS = 0.125f * LOG2E;
        int idx = (blockIdx.x - 256) * 256 + threadIdx.x;
        if (idx < 786432) {
            float v = qkv_w[idx];
            if (idx < 262144) v *= QS;              // q rows (o < 512)
            Wq[idx] = (f16)v;
        } else if (idx < 786432 + 262144) {
            Wo[idx - 786432] = (f16)out_w[idx - 786432];
        } else if (idx < 786432 + 262144 + 1536) {
            int i = idx - 786432 - 262144;
            float v = qkv_b[i];
            if (i < 512) v *= QS;
            qkv_bs[i] = v;
        }
        return;
    }
    // ---- GroupNorm path ----
    int blk = blockIdx.x;
    int n = blk >> 5, g = blk & 31;
    size_t base = ((size_t)n * C_ + (size_t)g * CPG_) * HW_;
    const float4* xp4 = (const float4*)(x + base);
    float4 vals[16];
    float s1 = 0.f, s2 = 0.f;
#pragma unroll
    for (int r = 0; r < 16; r++) {
        float4 v = xp4[r * 256 + threadIdx.x];   // c_local = r, l = 4*tid..4*tid+3
        vals[r] = v;
        s1 += v.x + v.y + v.z + v.w;
        s2 += v.x * v.x + v.y * v.y + v.z * v.z + v.w * v.w;
    }
#pragma unroll
    for (int off = 32; off > 0; off >>= 1) {
        s1 += __shfl_down(s1, off, 64);
        s2 += __shfl_down(s2, off, 64);
    }
    int wave = threadIdx.x >> 6, lane = threadIdx.x & 63;
    if (lane == 0) { red1[wave] = s1; red2[wave] = s2; }
    __syncthreads();
    if (threadIdx.x == 0) {
        float t1 = red1[0] + red1[1] + red1[2] + red1[3];
        float t2 = red2[0] + red2[1] + red2[2] + red2[3];
        float mean = t1 * (1.f / 16384.f);
        float var  = t2 * (1.f / 16384.f) - mean * mean;
        sm = mean;
        srstd = rsqrtf(var + 1e-5f);
    }
    __syncthreads();
    float mean = sm, rstd = srstd;
    float av[16], bbv[16];
#pragma unroll
    for (int r = 0; r < 16; r++) {
        int c = g * CPG_ + r;
        av[r] = gw[c] * rstd;
        bbv[r] = gb[c] - mean * av[r];
    }
    f16x8 lo[4], hi[4];
#pragma unroll
    for (int r = 0; r < 16; r++) {
        float4 v = vals[r];
        float a = av[r], bb = bbv[r];
        f16 e0 = (f16)(v.x * a + bb), e1 = (f16)(v.y * a + bb);
        f16 e2 = (f16)(v.z * a + bb), e3 = (f16)(v.w * a + bb);
        if (r < 8) { lo[0][r] = e0; lo[1][r] = e1; lo[2][r] = e2; lo[3][r] = e3; }
        else { hi[0][r - 8] = e0; hi[1][r - 8] = e1; hi[2][r - 8] = e2; hi[3][r - 8] = e3; }
    }
    // blocked store: [n][g][l][16], each thread 4 l's x 32 B contiguous = 128 B
    f16* xt = XT + (size_t)n * C_ * HW_ + ((size_t)g * HW_ + threadIdx.x * 4) * 16;
#pragma unroll
    for (int comp = 0; comp < 4; comp++) {
        *(f16x8*)&xt[comp * 16]     = lo[comp];
        *(f16x8*)&xt[comp * 16 + 8] = hi[comp];
    }
}

// ---------------- fp16 MFMA GEMM, depth-2 DMA pipeline, counted vmcnt ---------
// Y[o][l] = sum_c A[o][c] * B[...] + bias. BK=32, 16 K-steps, 3 LDS buffers.
// Step k: waitcnt vmcnt(G) certifies tile k landed (k+1 in flight); raw
// s_barrier collectivizes; stage tile k+2; compute tile k. Loads get 2 full
// compute phases to land (T4). Swizzle seg^=(row>>1)&3 (2-way max, free).
// s_setprio(1) around MFMA cluster (T5, pays with pipeline role-diversity).
// FINAL=false: BM=128, B blocked XT [n][cb][l][16], grid 768 (3/CU, 48KB).
// FINAL=true:  BM=64,  B w2T [n][l][512],           grid 512 (2/CU, 36KB).
template <bool FINAL>
__global__ __launch_bounds__(256, 4) void gemm_f16(const f16* __restrict__ A,
                                                   const f16* __restrict__ B,
                                                   const float* __restrict__ bias,
                                                   void* __restrict__ Yq,
                                                   f16* __restrict__ Yv) {
    constexpr int BM = FINAL ? 64 : 128;
    constexpr int MI = BM / 32;            // 16-row blocks per wave (wave owns BM/2)
    constexpr int ABUF = BM * 32 * 2;      // bytes per A buffer
    constexpr int BBUF = 128 * 32 * 2;     // 8192 bytes per B buffer
    constexpr int G = (BM / 64) + 2;       // per-thread GLOADs per stage
    // A bufs at 0,ABUF,2ABUF ; B bufs at 3ABUF + p*BBUF. !FINAL: 49152 (>=34816 T)
    __shared__ __align__(16) unsigned char smem[3 * ABUF + 3 * BBUF];
    int tid = threadIdx.x, lane = tid & 63, w = tid >> 6;
    int m = lane & 15, quad = lane >> 4;
    int ow0 = (w & 1) * (BM / 2), lw0 = (w >> 1) * 64;
    int flat = blockIdx.x;
    int n = flat & 7, rest = flat >> 3;
    int l0 = (rest & 7) * 128, o0 = (rest >> 3) * BM;
    const f16* Bn = B + (size_t)n * C_ * HW_;   // 512*1024 elements either layout

    f32x4 acc[MI][4];
#pragma unroll
    for (int i = 0; i < MI; i++)
#pragma unroll
        for (int j = 0; j < 4; j++)
#pragma unroll
            for (int r = 0; r < 4; r++) acc[i][j][r] = 0.f;

#define STAGE_STEP(c0_, pb_)                                                       \
    do {                                                                           \
        _Pragma("unroll")                                                          \
        for (int it = 0; it < BM / 64; it++) {                                     \
            int q = it * 256 + tid;                                                \
            int row = q >> 2, sg = (q & 3) ^ ((row >> 1) & 3);                     \
            GLOAD_LDS16(A + (size_t)(o0 + row) * 512 + (c0_) + sg * 8,             \
                        (f16*)(smem + (pb_) * ABUF) + (size_t)(it * 256 + w * 64) * 8); \
        }                                                                          \
        _Pragma("unroll")                                                          \
        for (int it = 0; it < 2; it++) {                                           \
            int q = it * 256 + tid;                                                \
            int row = q >> 2, sg = (q & 3) ^ ((row >> 1) & 3);                     \
            size_t baddr;                                                          \
            if (FINAL) {                                                           \
                baddr = (size_t)(l0 + row) * 512 + (c0_) + sg * 8;                 \
            } else {                                                               \
                int c = (c0_) + sg * 8;                                            \
                baddr = ((size_t)(c >> 4) * HW_ + (l0 + row)) * 16 + (c & 15);     \
            }                                                                      \
            GLOAD_LDS16(Bn + baddr,                                                \
                        (f16*)(smem + 3 * ABUF + (pb_) * BBUF) +                   \
                            (size_t)(it * 256 + w * 64) * 8);                      \
        }                                                                          \
    } while (0)

    STAGE_STEP(0, 0);                       // prologue: tiles 0 and 1 in flight
    STAGE_STEP(32, 1);

    for (int cs = 0; cs < 16; cs++) {
        int p = cs % 3;
        if (cs < 15) __builtin_amdgcn_s_waitcnt(0x0F70 | G);  // tile cs landed
        else         WAIT_VM0();                              // tail: only G left
        __builtin_amdgcn_s_barrier();       // all waves certified + done reading
        if (cs + 2 < 16) STAGE_STEP((cs + 2) * 32, (cs + 2) % 3);
        const f16* Asp = (const f16*)(smem + p * ABUF);
        const f16* Bsp = (const f16*)(smem + 3 * ABUF + p * BBUF);
        f16x8 af[MI], bf[4];
#pragma unroll
        for (int ib = 0; ib < MI; ib++) {
            int row = ow0 + ib * 16 + m;
            int sg = quad ^ ((row >> 1) & 3);
            af[ib] = *(const f16x8*)&Asp[row * 32 + sg * 8];
        }
#pragma unroll
        for (int jb = 0; jb < 4; jb++) {
            int row = lw0 + jb * 16 + m;
            int sg = quad ^ ((row >> 1) & 3);
            bf[jb] = *(const f16x8*)&Bsp[row * 32 + sg * 8];
        }
        __builtin_amdgcn_s_setprio(1);
#pragma unroll
        for (int ib = 0; ib < MI; ib++)
#pragma unroll
            for (int jb = 0; jb < 4; jb++)
                acc[ib][jb] = __builtin_amdgcn_mfma_f32_16x16x32_f16(
                    af[ib], bf[jb], acc[ib][jb], 0, 0, 0);
        __builtin_amdgcn_s_setprio(0);
    }
#undef STAGE_STEP

    float bv[MI][4];
#pragma unroll
    for (int ib = 0; ib < MI; ib++)
#pragma unroll
        for (int r = 0; r < 4; r++)
            bv[ib][r] = bias[o0 + ow0 + ib * 16 + quad * 4 + r];

    if (FINAL) {
        float* on = (float*)Yq + (size_t)n * C_ * HW_;
#pragma unroll
        for (int ib = 0; ib < MI; ib++)
#pragma unroll
            for (int jb = 0; jb < 4; jb++)
#pragma unroll
                for (int r = 0; r < 4; r++)
                    on[(size_t)(o0 + ow0 + ib * 16 + quad * 4 + r) * HW_ +
                       l0 + lw0 + jb * 16 + m] = acc[ib][jb][r] + bv[ib][r];
    } else if (o0 >= 1024) {
        f16* vn = Yv + (size_t)n * C_ * HW_;
#pragma unroll
        for (int ib = 0; ib < MI; ib++)
#pragma unroll
            for (int jb = 0; jb < 4; jb++)
#pragma unroll
                for (int r = 0; r < 4; r++)
                    vn[(size_t)(o0 - 1024 + ow0 + ib * 16 + quad * 4 + r) * HW_ +
                       l0 + lw0 + jb * 16 + m] = (f16)(acc[ib][jb][r] + bv[ib][r]);
    } else {
        __syncthreads();                 // staging reads done; reuse smem
        f16* T = (f16*)smem;             // [128][136]
#pragma unroll
        for (int ib = 0; ib < MI; ib++)
#pragma unroll
            for (int jb = 0; jb < 4; jb++) {
                f16x4 h;
#pragma unroll
                for (int r = 0; r < 4; r++) h[r] = (f16)(acc[ib][jb][r] + bv[ib][r]);
                int l = lw0 + jb * 16 + m;
                int oo = ow0 + ib * 16 + quad * 4;
                *(f16x4*)&T[l * 136 + oo] = h;
            }
        __syncthreads();
        f16* qn = (f16*)Yq + (size_t)n * HW_ * 1024;
#pragma unroll
        for (int rep = 0; rep < 8; rep++) {
            int idx = rep * 256 + tid;
            int l = idx >> 4, seg = idx & 15;
            f16x8 v = *(const f16x8*)&T[l * 136 + seg * 8];
            *(f16x8*)&qn[(size_t)(l0 + l) * 1024 + o0 + seg * 8] = v;
        }
    }
}

// ---------------- Flash attention fp16 MFMA, 64-row i-tiles ----------------
// S^T form (mfma(K,Q)); 2-buffer K/V DMA prefetch (1 phase deep). P consumed
// IN-REGISTER by 16x16x16 PV MFMAs. Row sums ALSO via MFMA (P x ones) ->
// lsum VALU chain and end-of-kernel shuffles deleted. exp via raw v_exp_f32,
// f32->f16 via packed cvt_pkrtz. LDS 32 KB -> 4 blocks/CU. setprio (T5).
// grid 1024 flat, XCD-swizzled.
__global__ __launch_bounds__(256, 4) void attn_f16(const f16* __restrict__ qkvT,
                                                   const f16* __restrict__ vbuf,
                                                   f16* __restrict__ w2T) {
    __shared__ __align__(16) unsigned char smem[32768];
    f16* Kb0  = (f16*)smem;                 // two 8 KB K buffers at 0, 8192
    f16* Vb0  = (f16*)(smem + 16384);       // two 8 KB V buffers at 16384, 24576
    f16* LDSo = (f16*)smem;                 // epilogue alias of K area (8 KB)

    int tid = threadIdx.x;
    int lane = tid & 63, wave = tid >> 6;
    int m = lane & 15, quad = lane >> 4;
    // XCD swizzle: flat = ((itile*8 + bh_hi)*8) + xcd ; bh = bh_hi*8 + xcd
    int flat = blockIdx.x;                  // 1024 blocks
    int xcd = flat & 7, slot = flat >> 3;
    int itile = slot >> 3, bh = (slot & 7) * 8 + xcd;
    int n = bh >> 3, head = bh & 7;
    int i0 = itile * 64;
    const f16* qb = qkvT + (size_t)n * HW_ * 1024 + head * 64;
    const f16* kb = qb + 512;
    const f16* vb = vbuf + (size_t)n * C_ * HW_ + (size_t)head * 64 * HW_;

    // Q fragments for this wave's strip (rows i0 + wave*16 + m)
    const f16* qr = qb + (size_t)(i0 + wave * 16 + m) * 1024;
    f16x8 aq0 = *(const f16x8*)&qr[quad * 8];
    f16x8 aq1 = *(const f16x8*)&qr[32 + quad * 8];

    // stage tile 0 -> buffer 0 (async)
#pragma unroll
    for (int it = 0; it < 2; it++) {
        int chunk = it * 256 + tid;
        int row = chunk >> 3, seg = chunk & 7;
        int segg = seg ^ (row & 7);
        GLOAD_LDS16(kb + (size_t)row * 1024 + segg * 8,
                    Kb0 + ((size_t)it * 256 + wave * 64) * 8);
        GLOAD_LDS16(vb + (size_t)row * HW_ + segg * 8,
                    Vb0 + ((size_t)it * 256 + wave * 64) * 8);
    }

    f32x4 oacc[4];
#pragma unroll
    for (int cb = 0; cb < 4; cb++)
#pragma unroll
        for (int r = 0; r < 4; r++) oacc[cb][r] = 0.f;
    f32x4 oaccL;                              // row-sum accumulator (P x ones)
#pragma unroll
    for (int r = 0; r < 4; r++) oaccL[r] = 0.f;
    const f16x4 vones = {(f16)1.f, (f16)1.f, (f16)1.f, (f16)1.f};
    int m7 = m & 7;

    for (int jt = 0; jt < 16; jt++) {
        int p = jt & 1;
        const f16* Kp = Kb0 + p * 4096;
        const f16* Vp = Vb0 + p * 4096;
        WAIT_VM0();        // drain own LDS-DMA before the barrier
        __syncthreads();   // all waves aligned => buffer p fully written
        if (jt < 15) {     // prefetch tile jt+1 into the other buffer
            int j0n = (jt + 1) * 64;
            f16* Kn = Kb0 + (1 - p) * 4096;
            f16* Vn = Vb0 + (1 - p) * 4096;
#pragma unroll
            for (int it = 0; it < 2; it++) {
                int chunk = it * 256 + tid;
                int row = chunk >> 3, seg = chunk & 7;
                int segg = seg ^ (row & 7);
                GLOAD_LDS16(kb + (size_t)(j0n + row) * 1024 + segg * 8,
                            Kn + ((size_t)it * 256 + wave * 64) * 8);
                GLOAD_LDS16(vb + (size_t)row * HW_ + j0n + segg * 8,
                            Vn + ((size_t)it * 256 + wave * 64) * 8);
            }
        }

        // K fragments (A-operand of S^T MFMA): rows j = jb*16 + m
        f16x8 kf[8];
#pragma unroll
        for (int jb = 0; jb < 4; jb++) {
            int row = jb * 16 + m;
            kf[jb]     = *(const f16x8*)&Kp[row * 64 + ((quad ^ (row & 7)) * 8)];
            kf[4 + jb] = *(const f16x8*)&Kp[row * 64 + (((4 + quad) ^ (row & 7)) * 8)];
        }

        // S^T = K Q^T : lane holds S[i=m][j = jb*16 + quad*4 + r]
        f32x4 sacc[4];
#pragma unroll
        for (int jb = 0; jb < 4; jb++)
#pragma unroll
            for (int r = 0; r < 4; r++) sacc[jb][r] = 0.f;
        __builtin_amdgcn_s_setprio(1);
#pragma unroll
        for (int jb = 0; jb < 4; jb++)
            sacc[jb] = __builtin_amdgcn_mfma_f32_16x16x32_f16(kf[jb], aq0,
                                                              sacc[jb], 0, 0, 0);
#pragma unroll
        for (int jb = 0; jb < 4; jb++)
            sacc[jb] = __builtin_amdgcn_mfma_f32_16x16x32_f16(kf[4 + jb], aq1,
                                                              sacc[jb], 0, 0, 0);
        __builtin_amdgcn_s_setprio(0);

        // max-free softmax: p = 2^s (log2 scale folded into Wq); pack P as
        // the x16 A-fragment DIRECTLY (lane layout matches, no cross-lane move)
        f16x4 pf[4];
#pragma unroll
        for (int jb = 0; jb < 4; jb++) {
            float p0 = EXP2F(sacc[jb][0]), p1 = EXP2F(sacc[jb][1]);
            float p2 = EXP2F(sacc[jb][2]), p3 = EXP2F(sacc[jb][3]);
            f16x2 lo2 = __builtin_bit_cast(f16x2, __builtin_amdgcn_cvt_pkrtz(p0, p1));
            f16x2 hi2 = __builtin_bit_cast(f16x2, __builtin_amdgcn_cvt_pkrtz(p2, p3));
            pf[jb][0] = lo2[0]; pf[jb][1] = lo2[1];
            pf[jb][2] = hi2[0]; pf[jb][3] = hi2[1];
        }

        // O += P V via 16x16x16; row sums += P x ones on the idle matrix pipe.
        // B-frag lane (m,q) needs V[jb*16+q*4+r][cb*16+m], contiguous f16x4 in
        // the Vb[c][j] row (seg-swizzle on c&7 == m&7).
        __builtin_amdgcn_s_setprio(1);
#pragma unroll
        for (int jb = 0; jb < 4; jb++) {
            int segb = jb * 2 + (quad >> 1);
            oaccL = __builtin_amdgcn_mfma_f32_16x16x16f16(pf[jb], vones,
                                                          oaccL, 0, 0, 0);
#pragma unroll
            for (int cb = 0; cb < 4; cb++) {
                f16x4 vf4 = *(const f16x4*)&Vp[(cb * 16 + m) * 64 +
                                               ((segb ^ m7) * 8) + (quad & 1) * 4];
                oacc[cb] = __builtin_amdgcn_mfma_f32_16x16x16f16(pf[jb], vf4,
                                                                 oacc[cb], 0, 0, 0);
            }
        }
        __builtin_amdgcn_s_setprio(0);
    }

    // oaccL[r] = rowsum(quad*4+r) in every lane — same rows as oacc[cb][r]
    float linv[4];
#pragma unroll
    for (int r = 0; r < 4; r++) linv[r] = 1.f / oaccL[r];

    WAIT_VM0();
    __syncthreads();   // everyone done with K/V buffers before aliasing
    // torch-reshape epilogue: local row li = wave*16+quad*4+r ->
    // ch-slot = li>>4 = wave ; s-coord = (li&15)*64 + cb*16 + m
#pragma unroll
    for (int cb = 0; cb < 4; cb++)
#pragma unroll
        for (int r = 0; r < 4; r++) {
            int sc = (quad * 4 + r) * 64 + cb * 16 + m;
            LDSo[sc * 4 + wave] = (f16)(oacc[cb][r] * linv[r]);
        }
    __syncthreads();
    f16* w2n = w2T + (size_t)n * HW_ * 512;
    int chbase = head * 64 + (i0 >> 4);     // itile*4 -> 8B aligned
#pragma unroll
    for (int it = 0; it < 4; it++) {
        int sc = it * 256 + tid;
        *(f16x4*)&w2n[(size_t)sc * 512 + chbase] = *(const f16x4*)&LDSo[sc * 4];
    }
}

extern "C" void kernel_launch(void* const* d_in, const int* in_sizes, int n_in,
                              void* d_out, int out_size, void* d_ws, size_t ws_size,
                              hipStream_t stream) {
    (void)in_sizes; (void)n_in; (void)out_size; (void)ws_size;
    const float* x     = (const float*)d_in[0];
    const float* gw    = (const float*)d_in[1];
    const float* gb    = (const float*)d_in[2];
    const float* qkv_w = (const float*)d_in[3];
    const float* qkv_b = (const float*)d_in[4];
    const float* out_w = (const float*)d_in[5];
    const float* out_b = (const float*)d_in[6];
    float* out = (float*)d_out;
    char* ws = (char*)d_ws;

    const size_t MB = 1024 * 1024;
    f16*   qkvT   = (f16*)ws;                       // [8][1024][1024] q|k  (16 MB)
    f16*   XT     = (f16*)(ws + 16 * MB);           // blocked [8][32][1024][16] (8 MB)
    f16*   vbuf   = (f16*)(ws + 24 * MB);           // [8][512][1024]       (8 MB)
    f16*   w2T    = (f16*)(ws + 32 * MB);           // [8][1024][512]       (8 MB)
    f16*   Wq     = (f16*)(ws + 40 * MB);           // [1536][512]          (1.5 MB)
    f16*   Wo     = (f16*)(ws + 42 * MB);           // [512][512]           (0.5 MB)
    float* qkv_bs = (float*)(ws + 43 * MB);         // [1536]

    prep<<<dim3(256 + 4103), 256, 0, stream>>>(x, gw, gb, XT,
                                               qkv_w, out_w, qkv_b, Wq, Wo, qkv_bs);
    gemm_f16<false><<<dim3(768), 256, 0, stream>>>(Wq, XT, qkv_bs, (void*)qkvT, vbuf);
    attn_f16<<<dim3(1024), 256, 0, stream>>>(qkvT, vbuf, w2T);
    gemm_f16<true><<<dim3(512), 256, 0, stream>>>(Wo, w2T, out_b, (void*)out, nullptr);
}

// Round 7
// 137.631 us; speedup vs baseline: 1.1146x; 1.0226x over previous
//
#include <hip/hip_runtime.h>
#include <math.h>

#define N_    8
#define C_    512
#define HW_   1024
#define G_    32
#define CPG_  16
#define OC3_  1536
#define LOG2E 1.44269504f

typedef _Float16 f16;
typedef f16 f16x8 __attribute__((ext_vector_type(8)));
typedef f16 f16x4 __attribute__((ext_vector_type(4)));
typedef f16 f16x2 __attribute__((ext_vector_type(2)));
typedef float f32x4 __attribute__((ext_vector_type(4)));
typedef float f32x16 __attribute__((ext_vector_type(16)));

#if __has_builtin(__builtin_amdgcn_exp2f)
#define EXP2F(x) __builtin_amdgcn_exp2f(x)
#else
#define EXP2F(x) exp2f(x)
#endif

#define GLOAD_LDS16(g, l)                                                          \
    __builtin_amdgcn_global_load_lds(                                              \
        (const __attribute__((address_space(1))) unsigned int*)(const void*)(g),   \
        (__attribute__((address_space(3))) unsigned int*)(void*)(l), 16, 0, 0)

// s_waitcnt encodings: vmcnt in [3:0], expcnt=7 (no wait) in [6:4],
// lgkmcnt=15 (no wait) in [11:8]  ->  0x0F70 | vmcnt
#define WAIT_VM0() __builtin_amdgcn_s_waitcnt(0x0F70)

// ---------------- prep: GroupNorm+transpose (blocks 0..255) | weight pack (rest)
__global__ __launch_bounds__(256) void prep(const float* __restrict__ x,
                                            const float* __restrict__ gw,
                                            const float* __restrict__ gb,
                                            f16* __restrict__ XT,
                                            const float* __restrict__ qkv_w,
                                            const float* __restrict__ out_w,
                                            const float* __restrict__ qkv_b,
                                            f16* __restrict__ Wq,
                                            f16* __restrict__ Wo,
                                            float* __restrict__ qkv_bs) {
    __shared__ float red1[4], red2[4];
    __shared__ float sm, srstd;
    if (blockIdx.x >= 256) {   // ---- weight pack path ----
        const float QS = 0.125f * LOG2E;
        int idx = (blockIdx.x - 256) * 256 + threadIdx.x;
        if (idx < 786432) {
            float v = qkv_w[idx];
            if (idx < 262144) v *= QS;              // q rows (o < 512)
            Wq[idx] = (f16)v;
        } else if (idx < 786432 + 262144) {
            Wo[idx - 786432] = (f16)out_w[idx - 786432];
        } else if (idx < 786432 + 262144 + 1536) {
            int i = idx - 786432 - 262144;
            float v = qkv_b[i];
            if (i < 512) v *= QS;
            qkv_bs[i] = v;
        }
        return;
    }
    // ---- GroupNorm path ----
    int blk = blockIdx.x;
    int n = blk >> 5, g = blk & 31;
    size_t base = ((size_t)n * C_ + (size_t)g * CPG_) * HW_;
    const float4* xp4 = (const float4*)(x + base);
    float4 vals[16];
    float s1 = 0.f, s2 = 0.f;
#pragma unroll
    for (int r = 0; r < 16; r++) {
        float4 v = xp4[r * 256 + threadIdx.x];   // c_local = r, l = 4*tid..4*tid+3
        vals[r] = v;
        s1 += v.x + v.y + v.z + v.w;
        s2 += v.x * v.x + v.y * v.y + v.z * v.z + v.w * v.w;
    }
#pragma unroll
    for (int off = 32; off > 0; off >>= 1) {
        s1 += __shfl_down(s1, off, 64);
        s2 += __shfl_down(s2, off, 64);
    }
    int wave = threadIdx.x >> 6, lane = threadIdx.x & 63;
    if (lane == 0) { red1[wave] = s1; red2[wave] = s2; }
    __syncthreads();
    if (threadIdx.x == 0) {
        float t1 = red1[0] + red1[1] + red1[2] + red1[3];
        float t2 = red2[0] + red2[1] + red2[2] + red2[3];
        float mean = t1 * (1.f / 16384.f);
        float var  = t2 * (1.f / 16384.f) - mean * mean;
        sm = mean;
        srstd = rsqrtf(var + 1e-5f);
    }
    __syncthreads();
    float mean = sm, rstd = srstd;
    float av[16], bbv[16];
#pragma unroll
    for (int r = 0; r < 16; r++) {
        int c = g * CPG_ + r;
        av[r] = gw[c] * rstd;
        bbv[r] = gb[c] - mean * av[r];
    }
    f16x8 lo[4], hi[4];
#pragma unroll
    for (int r = 0; r < 16; r++) {
        float4 v = vals[r];
        float a = av[r], bb = bbv[r];
        f16 e0 = (f16)(v.x * a + bb), e1 = (f16)(v.y * a + bb);
        f16 e2 = (f16)(v.z * a + bb), e3 = (f16)(v.w * a + bb);
        if (r < 8) { lo[0][r] = e0; lo[1][r] = e1; lo[2][r] = e2; lo[3][r] = e3; }
        else { hi[0][r - 8] = e0; hi[1][r - 8] = e1; hi[2][r - 8] = e2; hi[3][r - 8] = e3; }
    }
    // blocked store: [n][g][l][16], each thread 4 l's x 32 B contiguous = 128 B
    f16* xt = XT + (size_t)n * C_ * HW_ + ((size_t)g * HW_ + threadIdx.x * 4) * 16;
#pragma unroll
    for (int comp = 0; comp < 4; comp++) {
        *(f16x8*)&xt[comp * 16]     = lo[comp];
        *(f16x8*)&xt[comp * 16 + 8] = hi[comp];
    }
}

// ---------------- fp16 MFMA GEMM, depth-2 DMA pipeline, counted vmcnt ---------
// Y[o][l] = sum_c A[o][c] * B[...] + bias. BK=32, 16 K-steps, 3 LDS buffers.
// V output (o0>=1024) is written with the within-16 column permutation
// l -> swap(bit2,bit3): attn's PV x32 k-order then matches P's natural lane
// layout with ZERO cross-lane movement (permutation folded into V layout).
template <bool FINAL>
__global__ __launch_bounds__(256, 4) void gemm_f16(const f16* __restrict__ A,
                                                   const f16* __restrict__ B,
                                                   const float* __restrict__ bias,
                                                   void* __restrict__ Yq,
                                                   f16* __restrict__ Yv) {
    constexpr int BM = FINAL ? 64 : 128;
    constexpr int MI = BM / 32;            // 16-row blocks per wave (wave owns BM/2)
    constexpr int ABUF = BM * 32 * 2;      // bytes per A buffer
    constexpr int BBUF = 128 * 32 * 2;     // 8192 bytes per B buffer
    constexpr int G = (BM / 64) + 2;       // per-thread GLOADs per stage
    __shared__ __align__(16) unsigned char smem[3 * ABUF + 3 * BBUF];
    int tid = threadIdx.x, lane = tid & 63, w = tid >> 6;
    int m = lane & 15, quad = lane >> 4;
    int ow0 = (w & 1) * (BM / 2), lw0 = (w >> 1) * 64;
    int flat = blockIdx.x;
    int n = flat & 7, rest = flat >> 3;
    int l0 = (rest & 7) * 128, o0 = (rest >> 3) * BM;
    const f16* Bn = B + (size_t)n * C_ * HW_;   // 512*1024 elements either layout

    f32x4 acc[MI][4];
#pragma unroll
    for (int i = 0; i < MI; i++)
#pragma unroll
        for (int j = 0; j < 4; j++)
#pragma unroll
            for (int r = 0; r < 4; r++) acc[i][j][r] = 0.f;

#define STAGE_STEP(c0_, pb_)                                                       \
    do {                                                                           \
        _Pragma("unroll")                                                          \
        for (int it = 0; it < BM / 64; it++) {                                     \
            int q = it * 256 + tid;                                                \
            int row = q >> 2, sg = (q & 3) ^ ((row >> 1) & 3);                     \
            GLOAD_LDS16(A + (size_t)(o0 + row) * 512 + (c0_) + sg * 8,             \
                        (f16*)(smem + (pb_) * ABUF) + (size_t)(it * 256 + w * 64) * 8); \
        }                                                                          \
        _Pragma("unroll")                                                          \
        for (int it = 0; it < 2; it++) {                                           \
            int q = it * 256 + tid;                                                \
            int row = q >> 2, sg = (q & 3) ^ ((row >> 1) & 3);                     \
            size_t baddr;                                                          \
            if (FINAL) {                                                           \
                baddr = (size_t)(l0 + row) * 512 + (c0_) + sg * 8;                 \
            } else {                                                               \
                int c = (c0_) + sg * 8;                                            \
                baddr = ((size_t)(c >> 4) * HW_ + (l0 + row)) * 16 + (c & 15);     \
            }                                                                      \
            GLOAD_LDS16(Bn + baddr,                                                \
                        (f16*)(smem + 3 * ABUF + (pb_) * BBUF) +                   \
                            (size_t)(it * 256 + w * 64) * 8);                      \
        }                                                                          \
    } while (0)

    STAGE_STEP(0, 0);                       // prologue: tiles 0 and 1 in flight
    STAGE_STEP(32, 1);

    for (int cs = 0; cs < 16; cs++) {
        int p = cs % 3;
        if (cs < 15) __builtin_amdgcn_s_waitcnt(0x0F70 | G);  // tile cs landed
        else         WAIT_VM0();                              // tail: only G left
        __builtin_amdgcn_s_barrier();       // all waves certified + done reading
        if (cs + 2 < 16) STAGE_STEP((cs + 2) * 32, (cs + 2) % 3);
        const f16* Asp = (const f16*)(smem + p * ABUF);
        const f16* Bsp = (const f16*)(smem + 3 * ABUF + p * BBUF);
        f16x8 af[MI], bf[4];
#pragma unroll
        for (int ib = 0; ib < MI; ib++) {
            int row = ow0 + ib * 16 + m;
            int sg = quad ^ ((row >> 1) & 3);
            af[ib] = *(const f16x8*)&Asp[row * 32 + sg * 8];
        }
#pragma unroll
        for (int jb = 0; jb < 4; jb++) {
            int row = lw0 + jb * 16 + m;
            int sg = quad ^ ((row >> 1) & 3);
            bf[jb] = *(const f16x8*)&Bsp[row * 32 + sg * 8];
        }
        __builtin_amdgcn_s_setprio(1);
#pragma unroll
        for (int ib = 0; ib < MI; ib++)
#pragma unroll
            for (int jb = 0; jb < 4; jb++)
                acc[ib][jb] = __builtin_amdgcn_mfma_f32_16x16x32_f16(
                    af[ib], bf[jb], acc[ib][jb], 0, 0, 0);
        __builtin_amdgcn_s_setprio(0);
    }
#undef STAGE_STEP

    float bv[MI][4];
#pragma unroll
    for (int ib = 0; ib < MI; ib++)
#pragma unroll
        for (int r = 0; r < 4; r++)
            bv[ib][r] = bias[o0 + ow0 + ib * 16 + quad * 4 + r];

    if (FINAL) {
        float* on = (float*)Yq + (size_t)n * C_ * HW_;
#pragma unroll
        for (int ib = 0; ib < MI; ib++)
#pragma unroll
            for (int jb = 0; jb < 4; jb++)
#pragma unroll
                for (int r = 0; r < 4; r++)
                    on[(size_t)(o0 + ow0 + ib * 16 + quad * 4 + r) * HW_ +
                       l0 + lw0 + jb * 16 + m] = acc[ib][jb][r] + bv[ib][r];
    } else if (o0 >= 1024) {
        // V output: permute within-16 column (swap bits 2,3) for attn PV layout
        int mp = (m & 3) | ((m & 4) << 1) | ((m & 8) >> 1);
        f16* vn = Yv + (size_t)n * C_ * HW_;
#pragma unroll
        for (int ib = 0; ib < MI; ib++)
#pragma unroll
            for (int jb = 0; jb < 4; jb++)
#pragma unroll
                for (int r = 0; r < 4; r++)
                    vn[(size_t)(o0 - 1024 + ow0 + ib * 16 + quad * 4 + r) * HW_ +
                       l0 + lw0 + jb * 16 + mp] = (f16)(acc[ib][jb][r] + bv[ib][r]);
    } else {
        __syncthreads();                 // staging reads done; reuse smem
        f16* T = (f16*)smem;             // [128][136]
#pragma unroll
        for (int ib = 0; ib < MI; ib++)
#pragma unroll
            for (int jb = 0; jb < 4; jb++) {
                f16x4 h;
#pragma unroll
                for (int r = 0; r < 4; r++) h[r] = (f16)(acc[ib][jb][r] + bv[ib][r]);
                int l = lw0 + jb * 16 + m;
                int oo = ow0 + ib * 16 + quad * 4;
                *(f16x4*)&T[l * 136 + oo] = h;
            }
        __syncthreads();
        f16* qn = (f16*)Yq + (size_t)n * HW_ * 1024;
#pragma unroll
        for (int rep = 0; rep < 8; rep++) {
            int idx = rep * 256 + tid;
            int l = idx >> 4, seg = idx & 15;
            f16x8 v = *(const f16x8*)&T[l * 136 + seg * 8];
            *(f16x8*)&qn[(size_t)(l0 + l) * 1024 + o0 + seg * 8] = v;
        }
    }
}

// ---------------- Flash attention fp16, 32-row strips, 32x32x16 MFMAs --------
// Wave owns 32 i-rows; block = 4 waves = 128 rows; grid 512 (2/CU, 32 KB LDS).
// QK^T: S^T = K·Q^T via x32 (A=K rows j, B=Q^T; D: col=i=lane&31,
// row j=(reg&3)+8(reg>>2)+4(lane>>5)). PV: O^T = V^T·P via x32 with V's
// k-order permuted (bit2<->bit3 within 16, baked into vbuf by gemm) so the
// P B-frag is sacc regs IN ORDER — zero cross-lane movement, P never in LDS.
// Per iter per wave: 8 K-b128 + 8 V-b128 reads, 20 x32 MFMAs (incl. ones-
// rowsum on the matrix pipe). LDS reads/row HALVED vs 16-row strips.
__global__ __launch_bounds__(256, 4) void attn_f16(const f16* __restrict__ qkvT,
                                                   const f16* __restrict__ vbuf,
                                                   f16* __restrict__ w2T) {
    __shared__ __align__(16) unsigned char smem[32768];
    f16* Kb0  = (f16*)smem;                 // two 8 KB K buffers at 0, 8192
    f16* Vb0  = (f16*)(smem + 16384);       // two 8 KB V buffers at 16384, 24576
    f16* LDSo = (f16*)smem;                 // epilogue alias (16 KB: [1024][8])

    int tid = threadIdx.x;
    int lane = tid & 63, wave = tid >> 6;
    int l31 = lane & 31, hi = lane >> 5;
    // XCD swizzle: 512 blocks; bh = bh_hi*8 + xcd
    int flat = blockIdx.x;
    int xcd = flat & 7, slot = flat >> 3;          // slot 0..63
    int itile = slot >> 3, bh = (slot & 7) * 8 + xcd;
    int n = bh >> 3, head = bh & 7;
    int i0 = itile * 128;
    const f16* qb = qkvT + (size_t)n * HW_ * 1024 + head * 64;
    const f16* kb = qb + 512;
    const f16* vb = vbuf + (size_t)n * C_ * HW_ + (size_t)head * 64 * HW_;

    // Q fragments (B-operand): lane: Q[i=l31][d = dc*16 + hi*8 + e], i per wave
    f16x8 aq[4];
    {
        const f16* qr = qb + (size_t)(i0 + wave * 32 + l31) * 1024;
#pragma unroll
        for (int dc = 0; dc < 4; dc++)
            aq[dc] = *(const f16x8*)&qr[dc * 16 + hi * 8];
    }

    // stage tile 0 -> buffer 0 (async); K LDS [64 j][64 d], V LDS [64 c][64 jpos]
#pragma unroll
    for (int it = 0; it < 2; it++) {
        int chunk = it * 256 + tid;
        int row = chunk >> 3, seg = chunk & 7;
        int segg = seg ^ (row & 7);
        GLOAD_LDS16(kb + (size_t)row * 1024 + segg * 8,
                    Kb0 + ((size_t)it * 256 + wave * 64) * 8);
        GLOAD_LDS16(vb + (size_t)row * HW_ + segg * 8,
                    Vb0 + ((size_t)it * 256 + wave * 64) * 8);
    }

    f32x16 oaccD[2], oaccL;
#pragma unroll
    for (int r = 0; r < 16; r++) { oaccD[0][r] = 0.f; oaccD[1][r] = 0.f; oaccL[r] = 0.f; }
    const f16x8 vones = {(f16)1.f, (f16)1.f, (f16)1.f, (f16)1.f,
                         (f16)1.f, (f16)1.f, (f16)1.f, (f16)1.f};

    for (int jt = 0; jt < 16; jt++) {
        int p = jt & 1;
        const f16* Kp = Kb0 + p * 4096;
        const f16* Vp = Vb0 + p * 4096;
        WAIT_VM0();        // drain own LDS-DMA before the barrier
        __syncthreads();   // all waves aligned => buffer p fully written
        if (jt < 15) {     // prefetch tile jt+1 into the other buffer
            int j0n = (jt + 1) * 64;
            f16* Kn = Kb0 + (1 - p) * 4096;
            f16* Vn = Vb0 + (1 - p) * 4096;
#pragma unroll
            for (int it = 0; it < 2; it++) {
                int chunk = it * 256 + tid;
                int row = chunk >> 3, seg = chunk & 7;
                int segg = seg ^ (row & 7);
                GLOAD_LDS16(kb + (size_t)(j0n + row) * 1024 + segg * 8,
                            Kn + ((size_t)it * 256 + wave * 64) * 8);
                GLOAD_LDS16(vb + (size_t)row * HW_ + j0n + segg * 8,
                            Vn + ((size_t)it * 256 + wave * 64) * 8);
            }
        }

        // ---- QK^T (x32): S^T[jh] over j = jh*32 + ..., d chunks of 16
        f32x16 s0, s1;
#pragma unroll
        for (int r = 0; r < 16; r++) { s0[r] = 0.f; s1[r] = 0.f; }
        __builtin_amdgcn_s_setprio(1);
#pragma unroll
        for (int dc = 0; dc < 4; dc++) {
            int row0 = l31, row1 = 32 + l31;
            int seg = dc * 2 + hi;
            f16x8 kf0 = *(const f16x8*)&Kp[row0 * 64 + ((seg ^ (row0 & 7)) * 8)];
            f16x8 kf1 = *(const f16x8*)&Kp[row1 * 64 + ((seg ^ (row1 & 7)) * 8)];
            s0 = __builtin_amdgcn_mfma_f32_32x32x16_f16(kf0, aq[dc], s0, 0, 0, 0);
            s1 = __builtin_amdgcn_mfma_f32_32x32x16_f16(kf1, aq[dc], s1, 0, 0, 0);
        }
        __builtin_amdgcn_s_setprio(0);

        // ---- max-free softmax: p = 2^s (scale folded into Wq); pack P as the
        // x32 B-frag directly: chunk q element e = exp(sacc[q>>1][(q&1)*8+e])
        f16x8 pfc[4];
#pragma unroll
        for (int q = 0; q < 4; q++) {
            f32x16 sv = (q < 2) ? s0 : s1;
            int bs = (q & 1) * 8;
#pragma unroll
            for (int t = 0; t < 4; t++) {
                float a = EXP2F(sv[bs + 2 * t]);
                float b = EXP2F(sv[bs + 2 * t + 1]);
                f16x2 pk = __builtin_bit_cast(f16x2, __builtin_amdgcn_cvt_pkrtz(a, b));
                pfc[q][2 * t]     = pk[0];
                pfc[q][2 * t + 1] = pk[1];
            }
        }

        // ---- PV (x32): O^T[c][i] += V^T · P ; rowsum += ones · P (matrix pipe)
        __builtin_amdgcn_s_setprio(1);
#pragma unroll
        for (int q = 0; q < 4; q++) {
            oaccL = __builtin_amdgcn_mfma_f32_32x32x16_f16(vones, pfc[q],
                                                           oaccL, 0, 0, 0);
#pragma unroll
            for (int t = 0; t < 2; t++) {
                int c = t * 32 + l31;
                int seg = q * 2 + hi;
                f16x8 vf = *(const f16x8*)&Vp[c * 64 + ((seg ^ (c & 7)) * 8)];
                oaccD[t] = __builtin_amdgcn_mfma_f32_32x32x16_f16(vf, pfc[q],
                                                                  oaccD[t], 0, 0, 0);
            }
        }
        __builtin_amdgcn_s_setprio(0);
    }

    // lane holds O^T[c][i=l31] for 32 c's; rowsum in oaccL (all regs equal)
    float linv = 1.f / oaccL[0];

    WAIT_VM0();
    __syncthreads();   // everyone done with K/V buffers before aliasing
    // torch-reshape epilogue: global ch = head*64 + (i>>4); s = (i&15)*64 + cc
    // block covers 8 consecutive ch -> LDSo [1024 s][8 ch-slot]
#pragma unroll
    for (int t = 0; t < 2; t++)
#pragma unroll
        for (int r = 0; r < 16; r++) {
            int cc = t * 32 + (r & 3) + 8 * (r >> 2) + 4 * hi;
            int il = wave * 32 + l31;
            int sc = (il & 15) * 64 + cc;
            LDSo[sc * 8 + (il >> 4)] = (f16)(oaccD[t][r] * linv);
        }
    __syncthreads();
    f16* w2n = w2T + (size_t)n * HW_ * 512;
    int chbase = head * 64 + itile * 8;     // 8-aligned -> 16B-aligned stores
#pragma unroll
    for (int it = 0; it < 4; it++) {
        int sc = it * 256 + tid;
        *(f16x8*)&w2n[(size_t)sc * 512 + chbase] = *(const f16x8*)&LDSo[sc * 8];
    }
}

extern "C" void kernel_launch(void* const* d_in, const int* in_sizes, int n_in,
                              void* d_out, int out_size, void* d_ws, size_t ws_size,
                              hipStream_t stream) {
    (void)in_sizes; (void)n_in; (void)out_size; (void)ws_size;
    const float* x     = (const float*)d_in[0];
    const float* gw    = (const float*)d_in[1];
    const float* gb    = (const float*)d_in[2];
    const float* qkv_w = (const float*)d_in[3];
    const float* qkv_b = (const float*)d_in[4];
    const float* out_w = (const float*)d_in[5];
    const float* out_b = (const float*)d_in[6];
    float* out = (float*)d_out;
    char* ws = (char*)d_ws;

    const size_t MB = 1024 * 1024;
    f16*   qkvT   = (f16*)ws;                       // [8][1024][1024] q|k  (16 MB)
    f16*   XT     = (f16*)(ws + 16 * MB);           // blocked [8][32][1024][16] (8 MB)
    f16*   vbuf   = (f16*)(ws + 24 * MB);           // [8][512][1024] (j-permuted) (8 MB)
    f16*   w2T    = (f16*)(ws + 32 * MB);           // [8][1024][512]       (8 MB)
    f16*   Wq     = (f16*)(ws + 40 * MB);           // [1536][512]          (1.5 MB)
    f16*   Wo     = (f16*)(ws + 42 * MB);           // [512][512]           (0.5 MB)
    float* qkv_bs = (float*)(ws + 43 * MB);         // [1536]

    prep<<<dim3(256 + 4103), 256, 0, stream>>>(x, gw, gb, XT,
                                               qkv_w, out_w, qkv_b, Wq, Wo, qkv_bs);
    gemm_f16<false><<<dim3(768), 256, 0, stream>>>(Wq, XT, qkv_bs, (void*)qkvT, vbuf);
    attn_f16<<<dim3(512), 256, 0, stream>>>(qkvT, vbuf, w2T);
    gemm_f16<true><<<dim3(512), 256, 0, stream>>>(Wo, w2T, out_b, (void*)out, nullptr);
}